// Round 10
// baseline (232.149 us; speedup 1.0000x reference)
//
#include <hip/hip_runtime.h>

// Problem constants (fixed by reference)
#define H    256
#define HE   64
#define NPB  512         // nodes per batch
#define NA   512         // total anchors (8 batches * 64)
#define MU_STEP (20.0f / 63.0f)
#define INV_SIG 3.2f     // 1/0.3125
#define G_LD 384
#define NF_LD 264        // padded LDS row stride (264%32==8 -> 2-way only)

// workspace float offsets
#define OFF_G    0          // 320x384
#define OFF_KT   122880     // [c][vrow] 320*256
#define OFF_W1T  204800     // 256*512
#define OFF_W2T  335872     // 512*512
#define OFF_W3T  598016     // 512*256
#define OFF_AF1  729088     // 512*256

// ---------------------------------------------------------------------------
__device__ __forceinline__ float wave_sum(float v) {
#pragma unroll
    for (int o = 32; o; o >>= 1) v += __shfl_xor(v, o, 64);
    return v;
}
__device__ __forceinline__ float wave_max(float v) {
#pragma unroll
    for (int o = 32; o; o >>= 1) v = fmaxf(v, __shfl_xor(v, o, 64));
    return v;
}
__device__ __forceinline__ float block_sum(float v, float* red4, int t) {
    v = wave_sum(v);
    if ((t & 63) == 0) red4[t >> 6] = v;
    __syncthreads();
    v = red4[0] + red4[1] + red4[2] + red4[3];
    __syncthreads();
    return v;
}
__device__ __forceinline__ float block_max(float v, float* red4, int t) {
    v = wave_max(v);
    if ((t & 63) == 0) red4[t >> 6] = v;
    __syncthreads();
    v = fmaxf(fmaxf(red4[0], red4[1]), fmaxf(red4[2], red4[3]));
    __syncthreads();
    return v;
}
__device__ __forceinline__ float block_sum512(float v, float* red8, int t) {
    v = wave_sum(v);
    if ((t & 63) == 0) red8[t >> 6] = v;
    __syncthreads();
    v = red8[0] + red8[1] + red8[2] + red8[3]
      + red8[4] + red8[5] + red8[6] + red8[7];
    __syncthreads();
    return v;
}

// ---------------------------------------------------------------------------
// K1: weights prep (first dispatch — absorbs the fixed ~50us first-slot cost).
//  blocks 0..147: transposes (W1T, W2T, W3T, KT); 148..177: G GEMM.
//  G[j][n] = sum_c [Wq|bq][c][j] * [Wkv|bkv_k][c][n]; row 256 = bias row.
// ---------------------------------------------------------------------------
__global__ void __launch_bounds__(256) prep_weights(
    const float* __restrict__ Wq,  const float* __restrict__ bq,
    const float* __restrict__ Wkv, const float* __restrict__ bkv,
    const float* __restrict__ W1, const float* __restrict__ W2,
    const float* __restrict__ W3,
    float* __restrict__ G, float* __restrict__ KT,
    float* __restrict__ W1T, float* __restrict__ W2T, float* __restrict__ W3T)
{
    __shared__ float lds[8192];              // 32 KB
    const int bid = blockIdx.x, t = threadIdx.x;

    if (bid < 148) {
        float (*tile)[65] = (float(*)[65])lds;
        const float* src; float* dst; int C, Rd, tr, tc;
        if (bid < 32)       { src = W1; dst = W1T; C = 256; Rd = 512; tr = bid >> 2; tc = bid & 3; }
        else if (bid < 96)  { int ti = bid - 32; src = W2; dst = W2T; C = 512; Rd = 512; tr = ti >> 3; tc = ti & 7; }
        else if (bid < 128) { int ti = bid - 96; src = W3; dst = W3T; C = 512; Rd = 256; tr = ti >> 3; tc = ti & 7; }
        else                { int ti = bid - 128; src = Wkv + 256 * 320; dst = KT; C = 320; Rd = 256; tr = ti / 5; tc = ti % 5; }
        const int lane = t & 63, rg = t >> 6;
#pragma unroll
        for (int i = 0; i < 16; ++i) {
            int r = rg * 16 + i;
            tile[r][lane] = src[(size_t)(tr * 64 + r) * C + tc * 64 + lane];
        }
        __syncthreads();
#pragma unroll
        for (int i = 0; i < 16; ++i) {
            int r = rg * 16 + i;
            dst[(size_t)(tc * 64 + r) * Rd + tr * 64 + lane] = tile[lane][r];
        }
    } else {
        float* Als = lds;            // [c][j] 64x64
        float* Bls = lds + 4096;     // [c][n] 64x64
        const int gb = bid - 148;    // 0..29  (5 j-tiles x 6 n-tiles)
        const int mt = gb / 6, nt = gb - mt * 6;
        const int m0 = mt * 64, n0 = nt * 64;
        const int nq = t & 15, mq = t >> 4;
        float acc[4][4];
#pragma unroll
        for (int i = 0; i < 4; ++i)
#pragma unroll
            for (int k = 0; k < 4; ++k) acc[i][k] = 0.f;
        for (int c0 = 0; c0 < 256; c0 += 64) {
            __syncthreads();
            for (int idx = t; idx < 4096; idx += 256) {
                int cl = idx >> 6, el = idx & 63;
                int c = c0 + cl;
                int j = m0 + el;
                Als[idx] = (j < 256) ? Wq[(size_t)c * 256 + j] : (j == 256 ? bq[c] : 0.f);
                int n = n0 + el;
                Bls[idx] = (n < 320) ? Wkv[(size_t)c * 320 + n] : (n == 320 ? bkv[c] : 0.f);
            }
            __syncthreads();
#pragma unroll 4
            for (int cl = 0; cl < 64; ++cl) {
                const float* ar = Als + cl * 64 + mq * 4;
                const float* br = Bls + cl * 64 + nq * 4;
#pragma unroll
                for (int i = 0; i < 4; ++i)
#pragma unroll
                    for (int k = 0; k < 4; ++k)
                        acc[i][k] = fmaf(ar[i], br[k], acc[i][k]);
            }
        }
#pragma unroll
        for (int i = 0; i < 4; ++i) {
            int j = m0 + mq * 4 + i;
            float* gr = G + (size_t)j * G_LD + n0 + nq * 4;
            gr[0] = acc[i][0]; gr[1] = acc[i][1];
            gr[2] = acc[i][2]; gr[3] = acc[i][3];
        }
    }
}

// ---------------------------------------------------------------------------
// K2: fully fused attention per anchor. 512 blocks x 256 threads.
//  XCD-swizzled: a = (bid&7)*64 + (bid>>3) -> batch b pinned to XCD b
//  (assuming bid%8 XCD round-robin; perf heuristic only).
//  Phase B: [qW|qe|qbk] = af @ G + G[256,:]   (8-batched coalesced G loads)
//  Phase C: logits over 32 pipelined 16-node LDS tiles (padded stride 264)
//  Phase D: softmax + winner compaction + snf/rj + upd (KT coalesced) + LN1
// ---------------------------------------------------------------------------
__global__ void __launch_bounds__(256) attn_fused(
    const float* __restrict__ anchor_x, const float* __restrict__ node_x,
    const float* __restrict__ anchor_f, const float* __restrict__ node_f,
    const float* __restrict__ node_mask,
    const float* __restrict__ G, const float* __restrict__ KT,
    const float* __restrict__ bkv,
    const float* __restrict__ ln1_g, const float* __restrict__ ln1_b,
    float* __restrict__ af1_out)
{
    const int bid = blockIdx.x;
    const int a = (bid & 7) * 64 + (bid >> 3);      // XCD-local batch
    const int b = a >> 6, t = threadIdx.x;

    __shared__ float af_s[256], qW_s[256], qe_s[65];   // qe_s[64] = qbk
    __shared__ float nf_s[2][16 * NF_LD];              // padded double buffer
    __shared__ float d10_s[NPB], mf_s[NPB], lg_s[NPB], w_s[NPB];
    __shared__ float snf_s[256], rj_s[64], red[256], red4[4];
    __shared__ int   idx_s[NPB];
    __shared__ int   cnt_s;

    af_s[t] = anchor_f[(size_t)a * 256 + t];
    if (t == 0) cnt_s = 0;

    // d10 + mask factor for nodes t, t+256
    {
        const float ax0 = anchor_x[3 * a + 0];
        const float ax1 = anchor_x[3 * a + 1];
        const float ax2 = anchor_x[3 * a + 2];
#pragma unroll
        for (int nn = 0; nn < 2; ++nn) {
            int n = t + nn * 256, ng = b * NPB + n;
            float dx = ax0 - node_x[3 * ng + 0] + 1e-8f;
            float dy = ax1 - node_x[3 * ng + 1] + 1e-8f;
            float dz = ax2 - node_x[3 * ng + 2] + 1e-8f;
            d10_s[n] = sqrtf(dx * dx + dy * dy + dz * dz) * 0.1f;
            mf_s[n]  = (node_mask[ng] - 1.0f) * 1000000.0f;
        }
    }
    __syncthreads();   // af_s ready

    // ---- Phase B: qW[t], qe[t<64], qbk(t==64) from G (batched loads) ----
    {
        float acc0 = G[(size_t)256 * G_LD + t];
        const bool hb = (t <= 64);
        float acc1 = hb ? G[(size_t)256 * G_LD + 256 + t] : 0.f;
        for (int c = 0; c < 256; c += 8) {
            float a8[8], b8[8];
#pragma unroll
            for (int u = 0; u < 8; ++u) a8[u] = G[(size_t)(c + u) * G_LD + t];
            if (hb) {
#pragma unroll
                for (int u = 0; u < 8; ++u) b8[u] = G[(size_t)(c + u) * G_LD + 256 + t];
            }
#pragma unroll
            for (int u = 0; u < 8; ++u) {
                float av = af_s[c + u];
                acc0 = fmaf(av, a8[u], acc0);
                if (hb) acc1 = fmaf(av, b8[u], acc1);
            }
        }
        qW_s[t] = acc0;
        if (t <= 64) qe_s[t] = acc1;
    }

    // preload tile 0 (16 nodes x 256 floats = 1024 float4)
    const float4* src0 = (const float4*)(node_f + (size_t)(b * NPB) * 256);
    float4 rA = src0[t], rB = src0[t + 256], rC = src0[t + 512], rD = src0[t + 768];

    __syncthreads();   // qW_s / qe_s ready

    const float qbk = qe_s[64];
    const int n16 = t >> 4, kc = t & 15;
    // padded float4 store positions: src p = row*64+col4 -> dst row*66+col4
    const int dA = (t >> 6) * 66 + (t & 63);
    const int dB = ((t + 256) >> 6) * 66 + (t & 63);
    const int dC = ((t + 512) >> 6) * 66 + (t & 63);
    const int dD = ((t + 768) >> 6) * 66 + (t & 63);

    {   // store tile 0
        float4* dst = (float4*)(nf_s[0]);
        dst[dA] = rA; dst[dB] = rB; dst[dC] = rC; dst[dD] = rD;
    }
    __syncthreads();

    // ---- Phase C: logits, pipelined tiles, ONE sync per tile ----
    for (int tile = 0; tile < 32; ++tile) {
        if (tile < 31) {
            const float4* s2 = (const float4*)(node_f + (size_t)(b * NPB + (tile + 1) * 16) * 256);
            rA = s2[t]; rB = s2[t + 256]; rC = s2[t + 512]; rD = s2[t + 768];
        }

        const float* nf = nf_s[tile & 1] + n16 * NF_LD;
        const int n = tile * 16 + n16;
        const float d10 = d10_s[n];
        float s = 0.f;
#pragma unroll
        for (int u = 0; u < 16; ++u) {
            int k = kc + 16 * u;               // 2-way LDS aliasing only (padded)
            s = fmaf(qW_s[k], nf[k], s);
        }
#pragma unroll
        for (int u = 0; u < 4; ++u) {
            int j = kc * 4 + u;
            float uu = (d10 - j * MU_STEP) * INV_SIG;
            s = fmaf(qe_s[j], __expf(-uu * uu), s);
        }
#pragma unroll
        for (int o = 1; o < 16; o <<= 1) s += __shfl_xor(s, o, 64);
        if (kc == 0) lg_s[n] = (s + qbk) * mf_s[n];

        if (tile < 31) {                       // store into the OTHER buffer
            float4* dst = (float4*)(nf_s[(tile + 1) & 1]);
            dst[dA] = rA; dst[dB] = rB; dst[dC] = rC; dst[dD] = rD;
        }
        __syncthreads();
    }

    // ---- Phase D: softmax + winners + upd + LN1 ----
    float lg0 = lg_s[t], lg1 = lg_s[t + 256];
    float gm = block_max(fmaxf(lg0, lg1), red4, t);
    float e0 = __expf(lg0 - gm), e1 = __expf(lg1 - gm);
    w_s[t] = e0; w_s[t + 256] = e1;
    float inv = 1.0f / block_sum(e0 + e1, red4, t);   // syncs publish w_s

    if (e0 > 0.f) { int p = atomicAdd(&cnt_s, 1); idx_s[p] = t; }
    if (e1 > 0.f) { int p = atomicAdd(&cnt_s, 1); idx_s[p] = t + 256; }
    __syncthreads();
    const int cnt = cnt_s;

    {   // snf[t] = sum_winners w_n * node_f[n, t]  (rows are L2-hot)
        float s = 0.f;
        const float* base = node_f + (size_t)(b * NPB) * 256 + t;
        for (int i = 0; i < cnt; ++i) {
            int n = idx_s[i];
            s += w_s[n] * base[(size_t)n * 256];
        }
        snf_s[t] = s;
    }
    {   // rj[j] = sum_winners w_n * rbf[n, j]  (d10 from LDS, bitwise same as C)
        int j = t & 63, g = t >> 6;
        float mu = j * MU_STEP;
        float r = 0.f;
        for (int i = g; i < cnt; i += 4) {
            int n = idx_s[i];
            float uu = (d10_s[n] - mu) * INV_SIG;
            r += w_s[n] * __expf(-uu * uu);
        }
        red[t] = r;
        __syncthreads();
        if (t < 64) rj_s[t] = red[t] + red[t + 64] + red[t + 128] + red[t + 192];
        __syncthreads();
    }

    float upd;
    {   // coalesced KT reads, 8-batched
        float u = 0.f;
        for (int c = 0; c < 256; c += 8) {
            float k8[8];
#pragma unroll
            for (int q = 0; q < 8; ++q) k8[q] = KT[(size_t)(c + q) * 256 + t];
#pragma unroll
            for (int q = 0; q < 8; ++q) u = fmaf(k8[q], snf_s[c + q], u);
        }
        float e = 0.f;
        for (int j = 0; j < 64; j += 8) {
            float k8[8];
#pragma unroll
            for (int q = 0; q < 8; ++q) k8[q] = KT[(size_t)(256 + j + q) * 256 + t];
#pragma unroll
            for (int q = 0; q < 8; ++q) e = fmaf(k8[q], rj_s[j + q], e);
        }
        upd = (u + e) * inv + bkv[256 + t];
    }

    float x    = af_s[t] + upd;
    float mean = block_sum(x, red4, t) * (1.0f / 256.0f);
    float xc   = x - mean;
    float var  = block_sum(xc * xc, red4, t) * (1.0f / 256.0f);
    af1_out[(size_t)a * 256 + t] = xc * rsqrtf(var + 1e-5f) * ln1_g[t] + ln1_b[t];
}

// ---------------------------------------------------------------------------
// K3: fused MLP (3 layers) + residual + LN2.  256 blocks x 512 threads,
// 2 anchors/block (full chip coverage); 8-batched coalesced WT loads.
// ---------------------------------------------------------------------------
__global__ void __launch_bounds__(512) mlp_fused(
    const float* __restrict__ af1,
    const float* __restrict__ W1T, const float* __restrict__ b1,
    const float* __restrict__ W2T, const float* __restrict__ b2,
    const float* __restrict__ W3T, const float* __restrict__ b3,
    const float* __restrict__ g2,  const float* __restrict__ bb2,
    float* __restrict__ out)
{
    __shared__ float af_s[2 * 256];
    __shared__ float m1_s[2 * 512];
    __shared__ float m2_s[2 * 512];
    __shared__ float red8[8];
    const int t = threadIdx.x;
    const int a0 = blockIdx.x * 2;

    if (t < 128) ((float4*)af_s)[t] = ((const float4*)(af1 + (size_t)a0 * 256))[t];
    __syncthreads();

    // ---- L1: m1[p][t] = relu(b1[t] + sum_k af[p][k]*W1T[k][t]) ----
    {
        float bv = b1[t];
        float acc0 = bv, acc1 = bv;
        const float* w = W1T + t;
        for (int k = 0; k < 256; k += 8) {
            float w8[8];
#pragma unroll
            for (int u = 0; u < 8; ++u) w8[u] = w[(size_t)(k + u) * 512];
#pragma unroll
            for (int u = 0; u < 8; ++u) {
                acc0 = fmaf(af_s[k + u],       w8[u], acc0);
                acc1 = fmaf(af_s[256 + k + u], w8[u], acc1);
            }
        }
        m1_s[t]       = fmaxf(acc0, 0.f);
        m1_s[512 + t] = fmaxf(acc1, 0.f);
    }
    __syncthreads();

    // ---- L2: m2[p][t] = relu(b2[t] + sum_k m1[p][k]*W2T[k][t]) ----
    {
        float bv = b2[t];
        float acc0 = bv, acc1 = bv;
        const float* w = W2T + t;
        for (int k = 0; k < 512; k += 8) {
            float w8[8];
#pragma unroll
            for (int u = 0; u < 8; ++u) w8[u] = w[(size_t)(k + u) * 512];
#pragma unroll
            for (int u = 0; u < 8; ++u) {
                acc0 = fmaf(m1_s[k + u],       w8[u], acc0);
                acc1 = fmaf(m1_s[512 + k + u], w8[u], acc1);
            }
        }
        m2_s[t]       = fmaxf(acc0, 0.f);
        m2_s[512 + t] = fmaxf(acc1, 0.f);
    }
    __syncthreads();

    // ---- L3 split-k halves: y[p][th] = b3 + sum_k m2[p][k]*W3T[k][th] ----
    const int th = t & 255, kh = t >> 8;
    {
        float bv = (kh == 0) ? b3[th] : 0.f;
        float p0 = bv, p1 = bv;
        const float* w = W3T + th;
        const int kb = kh * 256;
        for (int k = 0; k < 256; k += 8) {
            float w8[8];
#pragma unroll
            for (int u = 0; u < 8; ++u) w8[u] = w[(size_t)(kb + k + u) * 256];
#pragma unroll
            for (int u = 0; u < 8; ++u) {
                p0 = fmaf(m2_s[kb + k + u],       w8[u], p0);
                p1 = fmaf(m2_s[512 + kb + k + u], w8[u], p1);
            }
        }
        m1_s[t]       = p0;    // m1_s dead: reuse for partial combine
        m1_s[512 + t] = p1;
    }
    __syncthreads();

    float y[2];
    float gv = 0.f, bv2 = 0.f;
    if (kh == 0) {
#pragma unroll
        for (int p = 0; p < 2; ++p)
            y[p] = m1_s[p * 512 + th] + m1_s[p * 512 + 256 + th] + af_s[p * 256 + th];
        gv = g2[th]; bv2 = bb2[th];
    }

#pragma unroll
    for (int p = 0; p < 2; ++p) {
        float s  = block_sum512((kh == 0) ? y[p] : 0.f, red8, t);
        float mn = s * (1.0f / 256.0f);
        float yc = (kh == 0) ? (y[p] - mn) : 0.f;
        float vr = block_sum512(yc * yc, red8, t) * (1.0f / 256.0f);
        if (kh == 0)
            out[(size_t)(a0 + p) * 256 + th] = yc * rsqrtf(vr + 1e-5f) * gv + bv2;
    }
}

// ---------------------------------------------------------------------------
extern "C" void kernel_launch(void* const* d_in, const int* in_sizes, int n_in,
                              void* d_out, int out_size, void* d_ws, size_t ws_size,
                              hipStream_t stream)
{
    const float* anchor_x  = (const float*)d_in[0];
    const float* node_x    = (const float*)d_in[1];
    const float* anchor_f  = (const float*)d_in[2];
    const float* node_f    = (const float*)d_in[3];
    const float* node_mask = (const float*)d_in[6];
    const float* Wq        = (const float*)d_in[7];
    const float* bq        = (const float*)d_in[8];
    const float* Wkv       = (const float*)d_in[9];
    const float* bkv       = (const float*)d_in[10];
    const float* ln1_g     = (const float*)d_in[11];
    const float* ln1_b     = (const float*)d_in[12];
    const float* W1        = (const float*)d_in[13];
    const float* b1        = (const float*)d_in[14];
    const float* W2        = (const float*)d_in[15];
    const float* b2        = (const float*)d_in[16];
    const float* W3        = (const float*)d_in[17];
    const float* b3        = (const float*)d_in[18];
    const float* ln2_g     = (const float*)d_in[19];
    const float* ln2_b     = (const float*)d_in[20];

    float* ws   = (float*)d_ws;
    float* G    = ws + OFF_G;
    float* KT   = ws + OFF_KT;
    float* W1T  = ws + OFF_W1T;
    float* W2T  = ws + OFF_W2T;
    float* W3T  = ws + OFF_W3T;
    float* af1  = ws + OFF_AF1;

    prep_weights<<<178, 256, 0, stream>>>(Wq, bq, Wkv, bkv, W1, W2, W3,
                                          G, KT, W1T, W2T, W3T);

    attn_fused<<<NA, 256, 0, stream>>>(anchor_x, node_x, anchor_f, node_f,
                                       node_mask, G, KT, bkv, ln1_g, ln1_b, af1);

    mlp_fused<<<256, 512, 0, stream>>>(af1, W1T, b1, W2T, b2, W3T, b3,
                                       ln2_g, ln2_b, (float*)d_out);
}

// Round 11
// 225.267 us; speedup vs baseline: 1.0306x; 1.0306x over previous
//
#include <hip/hip_runtime.h>

// Problem constants (fixed by reference)
#define H    256
#define HE   64
#define NPB  512         // nodes per batch
#define NA   512         // total anchors (8 batches * 64)
#define MU_STEP (20.0f / 63.0f)
#define INV_SIG 3.2f     // 1/0.3125
#define G_LD 384
#define NF_LD4 65        // LDS row stride in float4 (260 floats) — odd -> optimal banks

// workspace float offsets
#define OFF_G    0          // 320x384
#define OFF_KT   122880     // [c][vrow] 320*256
#define OFF_W1T  204800     // 256*512
#define OFF_W2T  335872     // 512*512
#define OFF_W3T  598016     // 512*256
#define OFF_AF1  729088     // 512*256

// ---------------------------------------------------------------------------
__device__ __forceinline__ float wave_sum(float v) {
#pragma unroll
    for (int o = 32; o; o >>= 1) v += __shfl_xor(v, o, 64);
    return v;
}
__device__ __forceinline__ float wave_max(float v) {
#pragma unroll
    for (int o = 32; o; o >>= 1) v = fmaxf(v, __shfl_xor(v, o, 64));
    return v;
}
__device__ __forceinline__ float block_sum512(float v, float* red8, int t) {
    v = wave_sum(v);
    if ((t & 63) == 0) red8[t >> 6] = v;
    __syncthreads();
    v = red8[0] + red8[1] + red8[2] + red8[3]
      + red8[4] + red8[5] + red8[6] + red8[7];
    __syncthreads();
    return v;
}
__device__ __forceinline__ float block_max512(float v, float* red8, int t) {
    v = wave_max(v);
    if ((t & 63) == 0) red8[t >> 6] = v;
    __syncthreads();
    v = fmaxf(fmaxf(fmaxf(red8[0], red8[1]), fmaxf(red8[2], red8[3])),
              fmaxf(fmaxf(red8[4], red8[5]), fmaxf(red8[6], red8[7])));
    __syncthreads();
    return v;
}

// ---------------------------------------------------------------------------
// K1: weights prep (first dispatch — absorbs the fixed ~50us first-slot cost).
//  blocks 0..147: transposes (W1T, W2T, W3T, KT); 148..177: G GEMM.
//  G[j][n] = sum_c [Wq|bq][c][j] * [Wkv|bkv_k][c][n]; row 256 = bias row.
// ---------------------------------------------------------------------------
__global__ void __launch_bounds__(256) prep_weights(
    const float* __restrict__ Wq,  const float* __restrict__ bq,
    const float* __restrict__ Wkv, const float* __restrict__ bkv,
    const float* __restrict__ W1, const float* __restrict__ W2,
    const float* __restrict__ W3,
    float* __restrict__ G, float* __restrict__ KT,
    float* __restrict__ W1T, float* __restrict__ W2T, float* __restrict__ W3T)
{
    __shared__ float lds[8192];              // 32 KB
    const int bid = blockIdx.x, t = threadIdx.x;

    if (bid < 148) {
        float (*tile)[65] = (float(*)[65])lds;
        const float* src; float* dst; int C, Rd, tr, tc;
        if (bid < 32)       { src = W1; dst = W1T; C = 256; Rd = 512; tr = bid >> 2; tc = bid & 3; }
        else if (bid < 96)  { int ti = bid - 32; src = W2; dst = W2T; C = 512; Rd = 512; tr = ti >> 3; tc = ti & 7; }
        else if (bid < 128) { int ti = bid - 96; src = W3; dst = W3T; C = 512; Rd = 256; tr = ti >> 3; tc = ti & 7; }
        else                { int ti = bid - 128; src = Wkv + 256 * 320; dst = KT; C = 320; Rd = 256; tr = ti / 5; tc = ti % 5; }
        const int lane = t & 63, rg = t >> 6;
#pragma unroll
        for (int i = 0; i < 16; ++i) {
            int r = rg * 16 + i;
            tile[r][lane] = src[(size_t)(tr * 64 + r) * C + tc * 64 + lane];
        }
        __syncthreads();
#pragma unroll
        for (int i = 0; i < 16; ++i) {
            int r = rg * 16 + i;
            dst[(size_t)(tc * 64 + r) * Rd + tr * 64 + lane] = tile[lane][r];
        }
    } else {
        float* Als = lds;            // [c][j] 64x64
        float* Bls = lds + 4096;     // [c][n] 64x64
        const int gb = bid - 148;    // 0..29  (5 j-tiles x 6 n-tiles)
        const int mt = gb / 6, nt = gb - mt * 6;
        const int m0 = mt * 64, n0 = nt * 64;
        const int nq = t & 15, mq = t >> 4;
        float acc[4][4];
#pragma unroll
        for (int i = 0; i < 4; ++i)
#pragma unroll
            for (int k = 0; k < 4; ++k) acc[i][k] = 0.f;
        for (int c0 = 0; c0 < 256; c0 += 64) {
            __syncthreads();
            for (int idx = t; idx < 4096; idx += 256) {
                int cl = idx >> 6, el = idx & 63;
                int c = c0 + cl;
                int j = m0 + el;
                Als[idx] = (j < 256) ? Wq[(size_t)c * 256 + j] : (j == 256 ? bq[c] : 0.f);
                int n = n0 + el;
                Bls[idx] = (n < 320) ? Wkv[(size_t)c * 320 + n] : (n == 320 ? bkv[c] : 0.f);
            }
            __syncthreads();
#pragma unroll 4
            for (int cl = 0; cl < 64; ++cl) {
                const float* ar = Als + cl * 64 + mq * 4;
                const float* br = Bls + cl * 64 + nq * 4;
#pragma unroll
                for (int i = 0; i < 4; ++i)
#pragma unroll
                    for (int k = 0; k < 4; ++k)
                        acc[i][k] = fmaf(ar[i], br[k], acc[i][k]);
            }
        }
#pragma unroll
        for (int i = 0; i < 4; ++i) {
            int j = m0 + mq * 4 + i;
            float* gr = G + (size_t)j * G_LD + n0 + nq * 4;
            gr[0] = acc[i][0]; gr[1] = acc[i][1];
            gr[2] = acc[i][2]; gr[3] = acc[i][3];
        }
    }
}

// ---------------------------------------------------------------------------
// K2: fused attention per anchor. 512 blocks x 512 threads (16 waves/CU).
//  XCD-swizzled: a = (bid&7)*64 + (bid>>3).
//  Phase B: threads t<=320 compute column t of [qW|qe|qbk] = af @ G + G[256,:]
//  Phase C: logits over 32 double-buffered 16-node LDS tiles, all-float4:
//           thread = (node t>>5, k-chunk t&31 of 8 floats); 5-shuffle reduce.
//  Phase D: softmax(512 thr) + winners + snf||rj parallel + upd + LN1.
// ---------------------------------------------------------------------------
__global__ void __launch_bounds__(512) attn_fused(
    const float* __restrict__ anchor_x, const float* __restrict__ node_x,
    const float* __restrict__ anchor_f, const float* __restrict__ node_f,
    const float* __restrict__ node_mask,
    const float* __restrict__ G, const float* __restrict__ KT,
    const float* __restrict__ bkv,
    const float* __restrict__ ln1_g, const float* __restrict__ ln1_b,
    float* __restrict__ af1_out)
{
    const int bid = blockIdx.x;
    const int a = (bid & 7) * 64 + (bid >> 3);      // XCD-local batch
    const int b = a >> 6, t = threadIdx.x;

    __shared__ __align__(16) float nf_s[2][16 * NF_LD4 * 4];  // 33.3 KB
    __shared__ __align__(16) float qWe_s[324];   // 0..255 qW, 256..319 qe, 320 qbk
    __shared__ float af_s[256];
    __shared__ float d10_s[NPB], mf_s[NPB], lg_s[NPB], w_s[NPB];
    __shared__ float snf_s[256], rj_s[64], red[256], red8[8];
    __shared__ int   idx_s[NPB];
    __shared__ int   cnt_s;

    if (t < 256) af_s[t] = anchor_f[(size_t)a * 256 + t];
    if (t == 0) cnt_s = 0;

    // Phase A: d10 + mask factor, one node per thread
    {
        const float ax0 = anchor_x[3 * a + 0];
        const float ax1 = anchor_x[3 * a + 1];
        const float ax2 = anchor_x[3 * a + 2];
        int ng = b * NPB + t;
        float dx = ax0 - node_x[3 * ng + 0] + 1e-8f;
        float dy = ax1 - node_x[3 * ng + 1] + 1e-8f;
        float dz = ax2 - node_x[3 * ng + 2] + 1e-8f;
        d10_s[t] = sqrtf(dx * dx + dy * dy + dz * dz) * 0.1f;
        mf_s[t]  = (node_mask[ng] - 1.0f) * 1000000.0f;
    }
    __syncthreads();   // af_s, cnt_s ready

    // preload tile 0 (16 nodes x 64 float4 = 1024 float4; 2 per thread)
    const float4* src0 = (const float4*)(node_f + (size_t)(b * NPB) * 256);
    float4 rA = src0[t], rB = src0[t + 512];

    // Phase B: column t of [qW|qe|qbk] (coalesced 8-batched G loads)
    if (t <= 320) {
        float acc = G[(size_t)256 * G_LD + t];
        for (int c = 0; c < 256; c += 8) {
            float g8[8];
#pragma unroll
            for (int u = 0; u < 8; ++u) g8[u] = G[(size_t)(c + u) * G_LD + t];
#pragma unroll
            for (int u = 0; u < 8; ++u) acc = fmaf(af_s[c + u], g8[u], acc);
        }
        qWe_s[t] = acc;
    }

    // store tile 0 (padded: float4 idx = row*65 + col)
    const int dA = (t >> 6) * NF_LD4 + (t & 63);
    const int dB = ((t >> 6) + 8) * NF_LD4 + (t & 63);
    {
        float4* dst = (float4*)(nf_s[0]);
        dst[dA] = rA; dst[dB] = rB;
    }
    __syncthreads();   // qWe_s + tile 0 ready

    const float qbk = qWe_s[320];
    const int n16 = t >> 5, kc = t & 31;
    const float4* qw4 = (const float4*)qWe_s;

    // ---- Phase C: logits, 32 double-buffered tiles, one sync each ----
    for (int tile = 0; tile < 32; ++tile) {
        if (tile < 31) {
            const float4* s2 = (const float4*)(node_f + (size_t)(b * NPB + (tile + 1) * 16) * 256);
            rA = s2[t]; rB = s2[t + 512];
        }

        const float4* nf4 = (const float4*)(nf_s[tile & 1]) + n16 * NF_LD4;
        float4 q0 = qw4[2 * kc], q1 = qw4[2 * kc + 1];
        float4 f0 = nf4[2 * kc], f1 = nf4[2 * kc + 1];
        float s = q0.x * f0.x + q0.y * f0.y + q0.z * f0.z + q0.w * f0.w
                + q1.x * f1.x + q1.y * f1.y + q1.z * f1.z + q1.w * f1.w;

        const int n = tile * 16 + n16;
        const float d10 = d10_s[n];
#pragma unroll
        for (int u = 0; u < 2; ++u) {
            int j = 2 * kc + u;
            float uu = (d10 - j * MU_STEP) * INV_SIG;
            s = fmaf(qWe_s[256 + j], __expf(-uu * uu), s);
        }
#pragma unroll
        for (int o = 1; o < 32; o <<= 1) s += __shfl_xor(s, o, 64);
        if (kc == 0) lg_s[n] = (s + qbk) * mf_s[n];

        if (tile < 31) {
            float4* dst = (float4*)(nf_s[(tile + 1) & 1]);
            dst[dA] = rA; dst[dB] = rB;
        }
        __syncthreads();
    }

    // ---- Phase D: softmax + winners + snf||rj + upd + LN1 ----
    float lg = lg_s[t];
    float gm = block_max512(lg, red8, t);
    float e  = __expf(lg - gm);
    w_s[t] = e;
    float inv = 1.0f / block_sum512(e, red8, t);   // syncs publish w_s

    if (e > 0.f) { int p = atomicAdd(&cnt_s, 1); idx_s[p] = t; }
    __syncthreads();
    const int cnt = cnt_s;

    if (t < 256) {   // snf[t] = sum_winners w_n * node_f[n, t]
        float s = 0.f;
        const float* base = node_f + (size_t)(b * NPB) * 256 + t;
        for (int i = 0; i < cnt; ++i) {
            int n = idx_s[i];
            s += w_s[n] * base[(size_t)n * 256];
        }
        snf_s[t] = s;
    } else {         // rj partials (4 groups x 64 j), in parallel with snf
        int j = (t - 256) & 63, g = (t - 256) >> 6;
        float mu = j * MU_STEP;
        float r = 0.f;
        for (int i = g; i < cnt; i += 4) {
            int n = idx_s[i];
            float uu = (d10_s[n] - mu) * INV_SIG;
            r += w_s[n] * __expf(-uu * uu);
        }
        red[t - 256] = r;
    }
    __syncthreads();
    if (t < 64) rj_s[t] = red[t] + red[t + 64] + red[t + 128] + red[t + 192];
    __syncthreads();

    float x = 0.f;
    if (t < 256) {
        float u = 0.f;
        for (int c = 0; c < 256; c += 8) {
            float k8[8];
#pragma unroll
            for (int q = 0; q < 8; ++q) k8[q] = KT[(size_t)(c + q) * 256 + t];
#pragma unroll
            for (int q = 0; q < 8; ++q) u = fmaf(k8[q], snf_s[c + q], u);
        }
        float ee = 0.f;
        for (int j = 0; j < 64; j += 8) {
            float k8[8];
#pragma unroll
            for (int q = 0; q < 8; ++q) k8[q] = KT[(size_t)(256 + j + q) * 256 + t];
#pragma unroll
            for (int q = 0; q < 8; ++q) ee = fmaf(k8[q], rj_s[j + q], ee);
        }
        x = af_s[t] + (u + ee) * inv + bkv[256 + t];
    }

    float mean = block_sum512(x, red8, t) * (1.0f / 256.0f);
    float xc   = (t < 256) ? (x - mean) : 0.f;
    float var  = block_sum512(xc * xc, red8, t) * (1.0f / 256.0f);
    if (t < 256)
        af1_out[(size_t)a * 256 + t] = xc * rsqrtf(var + 1e-5f) * ln1_g[t] + ln1_b[t];
}

// ---------------------------------------------------------------------------
// K3: fused MLP (3 layers) + residual + LN2.  256 blocks x 512 threads,
// 2 anchors/block; 8-batched coalesced WT loads.
// ---------------------------------------------------------------------------
__global__ void __launch_bounds__(512) mlp_fused(
    const float* __restrict__ af1,
    const float* __restrict__ W1T, const float* __restrict__ b1,
    const float* __restrict__ W2T, const float* __restrict__ b2,
    const float* __restrict__ W3T, const float* __restrict__ b3,
    const float* __restrict__ g2,  const float* __restrict__ bb2,
    float* __restrict__ out)
{
    __shared__ float af_s[2 * 256];
    __shared__ float m1_s[2 * 512];
    __shared__ float m2_s[2 * 512];
    __shared__ float red8[8];
    const int t = threadIdx.x;
    const int a0 = blockIdx.x * 2;

    if (t < 128) ((float4*)af_s)[t] = ((const float4*)(af1 + (size_t)a0 * 256))[t];
    __syncthreads();

    {
        float bv = b1[t];
        float acc0 = bv, acc1 = bv;
        const float* w = W1T + t;
        for (int k = 0; k < 256; k += 8) {
            float w8[8];
#pragma unroll
            for (int u = 0; u < 8; ++u) w8[u] = w[(size_t)(k + u) * 512];
#pragma unroll
            for (int u = 0; u < 8; ++u) {
                acc0 = fmaf(af_s[k + u],       w8[u], acc0);
                acc1 = fmaf(af_s[256 + k + u], w8[u], acc1);
            }
        }
        m1_s[t]       = fmaxf(acc0, 0.f);
        m1_s[512 + t] = fmaxf(acc1, 0.f);
    }
    __syncthreads();

    {
        float bv = b2[t];
        float acc0 = bv, acc1 = bv;
        const float* w = W2T + t;
        for (int k = 0; k < 512; k += 8) {
            float w8[8];
#pragma unroll
            for (int u = 0; u < 8; ++u) w8[u] = w[(size_t)(k + u) * 512];
#pragma unroll
            for (int u = 0; u < 8; ++u) {
                acc0 = fmaf(m1_s[k + u],       w8[u], acc0);
                acc1 = fmaf(m1_s[512 + k + u], w8[u], acc1);
            }
        }
        m2_s[t]       = fmaxf(acc0, 0.f);
        m2_s[512 + t] = fmaxf(acc1, 0.f);
    }
    __syncthreads();

    const int th = t & 255, kh = t >> 8;
    {
        float bv = (kh == 0) ? b3[th] : 0.f;
        float p0 = bv, p1 = bv;
        const float* w = W3T + th;
        const int kb = kh * 256;
        for (int k = 0; k < 256; k += 8) {
            float w8[8];
#pragma unroll
            for (int u = 0; u < 8; ++u) w8[u] = w[(size_t)(kb + k + u) * 256];
#pragma unroll
            for (int u = 0; u < 8; ++u) {
                p0 = fmaf(m2_s[kb + k + u],       w8[u], p0);
                p1 = fmaf(m2_s[512 + kb + k + u], w8[u], p1);
            }
        }
        m1_s[t]       = p0;    // m1_s dead: reuse for partial combine
        m1_s[512 + t] = p1;
    }
    __syncthreads();

    float y[2];
    float gv = 0.f, bv2 = 0.f;
    if (kh == 0) {
#pragma unroll
        for (int p = 0; p < 2; ++p)
            y[p] = m1_s[p * 512 + th] + m1_s[p * 512 + 256 + th] + af_s[p * 256 + th];
        gv = g2[th]; bv2 = bb2[th];
    }

#pragma unroll
    for (int p = 0; p < 2; ++p) {
        float s  = block_sum512((kh == 0) ? y[p] : 0.f, red8, t);
        float mn = s * (1.0f / 256.0f);
        float yc = (kh == 0) ? (y[p] - mn) : 0.f;
        float vr = block_sum512(yc * yc, red8, t) * (1.0f / 256.0f);
        if (kh == 0)
            out[(size_t)(a0 + p) * 256 + th] = yc * rsqrtf(vr + 1e-5f) * gv + bv2;
    }
}

// ---------------------------------------------------------------------------
extern "C" void kernel_launch(void* const* d_in, const int* in_sizes, int n_in,
                              void* d_out, int out_size, void* d_ws, size_t ws_size,
                              hipStream_t stream)
{
    const float* anchor_x  = (const float*)d_in[0];
    const float* node_x    = (const float*)d_in[1];
    const float* anchor_f  = (const float*)d_in[2];
    const float* node_f    = (const float*)d_in[3];
    const float* node_mask = (const float*)d_in[6];
    const float* Wq        = (const float*)d_in[7];
    const float* bq        = (const float*)d_in[8];
    const float* Wkv       = (const float*)d_in[9];
    const float* bkv       = (const float*)d_in[10];
    const float* ln1_g     = (const float*)d_in[11];
    const float* ln1_b     = (const float*)d_in[12];
    const float* W1        = (const float*)d_in[13];
    const float* b1        = (const float*)d_in[14];
    const float* W2        = (const float*)d_in[15];
    const float* b2        = (const float*)d_in[16];
    const float* W3        = (const float*)d_in[17];
    const float* b3        = (const float*)d_in[18];
    const float* ln2_g     = (const float*)d_in[19];
    const float* ln2_b     = (const float*)d_in[20];

    float* ws   = (float*)d_ws;
    float* G    = ws + OFF_G;
    float* KT   = ws + OFF_KT;
    float* W1T  = ws + OFF_W1T;
    float* W2T  = ws + OFF_W2T;
    float* W3T  = ws + OFF_W3T;
    float* af1  = ws + OFF_AF1;

    prep_weights<<<178, 256, 0, stream>>>(Wq, bq, Wkv, bkv, W1, W2, W3,
                                          G, KT, W1T, W2T, W3T);

    attn_fused<<<NA, 512, 0, stream>>>(anchor_x, node_x, anchor_f, node_f,
                                       node_mask, G, KT, bkv, ln1_g, ln1_b, af1);

    mlp_fused<<<256, 512, 0, stream>>>(af1, W1T, b1, W2T, b2, W3T, b3,
                                       ln2_g, ln2_b, (float*)d_out);
}

// Round 12
// 217.236 us; speedup vs baseline: 1.0686x; 1.0370x over previous
//
#include <hip/hip_runtime.h>

// Problem constants (fixed by reference)
#define H    256
#define HE   64
#define NPB  512         // nodes per batch
#define NA   512         // total anchors (8 batches * 64)
#define MU_STEP (20.0f / 63.0f)
#define INV_SIG 3.2f     // 1/0.3125
#define G_LD 384
#define NF_LD4 65        // LDS row stride in float4 (260 floats) — odd -> good banks

// workspace float offsets
#define OFF_G    0          // 320x384
#define OFF_KT   122880     // [c][vrow] 320*256
#define OFF_W1T  204800     // 256*512
#define OFF_W2T  335872     // 512*512
#define OFF_W3T  598016     // 512*256

// ---------------------------------------------------------------------------
__device__ __forceinline__ float wave_sum(float v) {
#pragma unroll
    for (int o = 32; o; o >>= 1) v += __shfl_xor(v, o, 64);
    return v;
}
__device__ __forceinline__ float wave_max(float v) {
#pragma unroll
    for (int o = 32; o; o >>= 1) v = fmaxf(v, __shfl_xor(v, o, 64));
    return v;
}
__device__ __forceinline__ float block_sum512(float v, float* red8, int t) {
    v = wave_sum(v);
    if ((t & 63) == 0) red8[t >> 6] = v;
    __syncthreads();
    v = red8[0] + red8[1] + red8[2] + red8[3]
      + red8[4] + red8[5] + red8[6] + red8[7];
    __syncthreads();
    return v;
}
__device__ __forceinline__ float block_max512(float v, float* red8, int t) {
    v = wave_max(v);
    if ((t & 63) == 0) red8[t >> 6] = v;
    __syncthreads();
    v = fmaxf(fmaxf(fmaxf(red8[0], red8[1]), fmaxf(red8[2], red8[3])),
              fmaxf(fmaxf(red8[4], red8[5]), fmaxf(red8[6], red8[7])));
    __syncthreads();
    return v;
}

// ---------------------------------------------------------------------------
// K1: weights prep (first dispatch — absorbs the fixed ~50us first-slot ramp).
//  blocks 0..147: transposes (W1T, W2T, W3T, KT); 148..177: G GEMM.
//  G[j][n] = sum_c [Wq|bq][c][j] * [Wkv|bkv_k][c][n]; row 256 = bias row.
// ---------------------------------------------------------------------------
__global__ void __launch_bounds__(256) prep_weights(
    const float* __restrict__ Wq,  const float* __restrict__ bq,
    const float* __restrict__ Wkv, const float* __restrict__ bkv,
    const float* __restrict__ W1, const float* __restrict__ W2,
    const float* __restrict__ W3,
    float* __restrict__ G, float* __restrict__ KT,
    float* __restrict__ W1T, float* __restrict__ W2T, float* __restrict__ W3T)
{
    __shared__ float lds[8192];              // 32 KB
    const int bid = blockIdx.x, t = threadIdx.x;

    if (bid < 148) {
        float (*tile)[65] = (float(*)[65])lds;
        const float* src; float* dst; int C, Rd, tr, tc;
        if (bid < 32)       { src = W1; dst = W1T; C = 256; Rd = 512; tr = bid >> 2; tc = bid & 3; }
        else if (bid < 96)  { int ti = bid - 32; src = W2; dst = W2T; C = 512; Rd = 512; tr = ti >> 3; tc = ti & 7; }
        else if (bid < 128) { int ti = bid - 96; src = W3; dst = W3T; C = 512; Rd = 256; tr = ti >> 3; tc = ti & 7; }
        else                { int ti = bid - 128; src = Wkv + 256 * 320; dst = KT; C = 320; Rd = 256; tr = ti / 5; tc = ti % 5; }
        const int lane = t & 63, rg = t >> 6;
#pragma unroll
        for (int i = 0; i < 16; ++i) {
            int r = rg * 16 + i;
            tile[r][lane] = src[(size_t)(tr * 64 + r) * C + tc * 64 + lane];
        }
        __syncthreads();
#pragma unroll
        for (int i = 0; i < 16; ++i) {
            int r = rg * 16 + i;
            dst[(size_t)(tc * 64 + r) * Rd + tr * 64 + lane] = tile[lane][r];
        }
    } else {
        float* Als = lds;            // [c][j] 64x64
        float* Bls = lds + 4096;     // [c][n] 64x64
        const int gb = bid - 148;    // 0..29  (5 j-tiles x 6 n-tiles)
        const int mt = gb / 6, nt = gb - mt * 6;
        const int m0 = mt * 64, n0 = nt * 64;
        const int nq = t & 15, mq = t >> 4;
        float acc[4][4];
#pragma unroll
        for (int i = 0; i < 4; ++i)
#pragma unroll
            for (int k = 0; k < 4; ++k) acc[i][k] = 0.f;
        for (int c0 = 0; c0 < 256; c0 += 64) {
            __syncthreads();
            for (int idx = t; idx < 4096; idx += 256) {
                int cl = idx >> 6, el = idx & 63;
                int c = c0 + cl;
                int j = m0 + el;
                Als[idx] = (j < 256) ? Wq[(size_t)c * 256 + j] : (j == 256 ? bq[c] : 0.f);
                int n = n0 + el;
                Bls[idx] = (n < 320) ? Wkv[(size_t)c * 320 + n] : (n == 320 ? bkv[c] : 0.f);
            }
            __syncthreads();
#pragma unroll 4
            for (int cl = 0; cl < 64; ++cl) {
                const float* ar = Als + cl * 64 + mq * 4;
                const float* br = Bls + cl * 64 + nq * 4;
#pragma unroll
                for (int i = 0; i < 4; ++i)
#pragma unroll
                    for (int k = 0; k < 4; ++k)
                        acc[i][k] = fmaf(ar[i], br[k], acc[i][k]);
            }
        }
#pragma unroll
        for (int i = 0; i < 4; ++i) {
            int j = m0 + mq * 4 + i;
            float* gr = G + (size_t)j * G_LD + n0 + nq * 4;
            gr[0] = acc[i][0]; gr[1] = acc[i][1];
            gr[2] = acc[i][2]; gr[3] = acc[i][3];
        }
    }
}

// ---------------------------------------------------------------------------
// K2: everything per anchor. 512 blocks x 512 threads.
//  attn (r11-verified): Phase A d10/mask; B [qW|qe|qbk]; C logits (32 dbuf
//  tiles, float4); D softmax + winners + snf||rj + upd + LN1 -> af1 in LDS.
//  Then in-block MLP L1/L2/L3 (8-batched coalesced WT loads) + LN2 -> out.
// ---------------------------------------------------------------------------
__global__ void __launch_bounds__(512) fused_all(
    const float* __restrict__ anchor_x, const float* __restrict__ node_x,
    const float* __restrict__ anchor_f, const float* __restrict__ node_f,
    const float* __restrict__ node_mask,
    const float* __restrict__ G, const float* __restrict__ KT,
    const float* __restrict__ bkv,
    const float* __restrict__ ln1_g, const float* __restrict__ ln1_b,
    const float* __restrict__ W1T, const float* __restrict__ b1,
    const float* __restrict__ W2T, const float* __restrict__ b2,
    const float* __restrict__ W3T, const float* __restrict__ b3,
    const float* __restrict__ g2,  const float* __restrict__ bb2,
    float* __restrict__ out)
{
    const int bid = blockIdx.x;
    const int a = (bid & 7) * 64 + (bid >> 3);      // XCD-local batch
    const int b = a >> 6, t = threadIdx.x;

    __shared__ __align__(16) float nf_s[2][16 * NF_LD4 * 4];  // 33.3 KB
    __shared__ __align__(16) float qWe_s[324];   // 0..255 qW, 256..319 qe, 320 qbk
    __shared__ float af_s[256];                  // anchor_f, later af1 (post-LN1)
    __shared__ float d10_s[NPB], mf_s[NPB], lg_s[NPB], w_s[NPB];
    __shared__ float snf_s[256], rj_s[64], red[256], red8[8];
    __shared__ float m1_s[512], m2_s[512];
    __shared__ int   idx_s[NPB];
    __shared__ int   cnt_s;

    if (t < 256) af_s[t] = anchor_f[(size_t)a * 256 + t];
    if (t == 0) cnt_s = 0;

    // Phase A: d10 + mask factor, one node per thread
    {
        const float ax0 = anchor_x[3 * a + 0];
        const float ax1 = anchor_x[3 * a + 1];
        const float ax2 = anchor_x[3 * a + 2];
        int ng = b * NPB + t;
        float dx = ax0 - node_x[3 * ng + 0] + 1e-8f;
        float dy = ax1 - node_x[3 * ng + 1] + 1e-8f;
        float dz = ax2 - node_x[3 * ng + 2] + 1e-8f;
        d10_s[t] = sqrtf(dx * dx + dy * dy + dz * dz) * 0.1f;
        mf_s[t]  = (node_mask[ng] - 1.0f) * 1000000.0f;
    }
    __syncthreads();   // af_s, cnt_s ready

    // preload tile 0 (16 nodes x 64 float4 = 1024 float4; 2 per thread)
    const float4* src0 = (const float4*)(node_f + (size_t)(b * NPB) * 256);
    float4 rA = src0[t], rB = src0[t + 512];

    // Phase B: column t of [qW|qe|qbk] (coalesced 8-batched G loads)
    if (t <= 320) {
        float acc = G[(size_t)256 * G_LD + t];
        for (int c = 0; c < 256; c += 8) {
            float g8[8];
#pragma unroll
            for (int u = 0; u < 8; ++u) g8[u] = G[(size_t)(c + u) * G_LD + t];
#pragma unroll
            for (int u = 0; u < 8; ++u) acc = fmaf(af_s[c + u], g8[u], acc);
        }
        qWe_s[t] = acc;
    }

    // store tile 0 (padded: float4 idx = row*65 + col)
    const int dA = (t >> 6) * NF_LD4 + (t & 63);
    const int dB = ((t >> 6) + 8) * NF_LD4 + (t & 63);
    {
        float4* dst = (float4*)(nf_s[0]);
        dst[dA] = rA; dst[dB] = rB;
    }
    __syncthreads();   // qWe_s + tile 0 ready

    const float qbk = qWe_s[320];
    const int n16 = t >> 5, kc = t & 31;
    const float4* qw4 = (const float4*)qWe_s;

    // ---- Phase C: logits, 32 double-buffered tiles, one sync each ----
    for (int tile = 0; tile < 32; ++tile) {
        if (tile < 31) {
            const float4* s2 = (const float4*)(node_f + (size_t)(b * NPB + (tile + 1) * 16) * 256);
            rA = s2[t]; rB = s2[t + 512];
        }

        const float4* nf4 = (const float4*)(nf_s[tile & 1]) + n16 * NF_LD4;
        float4 q0 = qw4[2 * kc], q1 = qw4[2 * kc + 1];
        float4 f0 = nf4[2 * kc], f1 = nf4[2 * kc + 1];
        float s = q0.x * f0.x + q0.y * f0.y + q0.z * f0.z + q0.w * f0.w
                + q1.x * f1.x + q1.y * f1.y + q1.z * f1.z + q1.w * f1.w;

        const int n = tile * 16 + n16;
        const float d10 = d10_s[n];
#pragma unroll
        for (int u = 0; u < 2; ++u) {
            int j = 2 * kc + u;
            float uu = (d10 - j * MU_STEP) * INV_SIG;
            s = fmaf(qWe_s[256 + j], __expf(-uu * uu), s);
        }
#pragma unroll
        for (int o = 1; o < 32; o <<= 1) s += __shfl_xor(s, o, 64);
        if (kc == 0) lg_s[n] = (s + qbk) * mf_s[n];

        if (tile < 31) {
            float4* dst = (float4*)(nf_s[(tile + 1) & 1]);
            dst[dA] = rA; dst[dB] = rB;
        }
        __syncthreads();
    }

    // ---- Phase D: softmax + winners + snf||rj + upd + LN1 ----
    float lg = lg_s[t];
    float gm = block_max512(lg, red8, t);
    float e  = __expf(lg - gm);
    w_s[t] = e;
    float inv = 1.0f / block_sum512(e, red8, t);   // syncs publish w_s

    if (e > 0.f) { int p = atomicAdd(&cnt_s, 1); idx_s[p] = t; }
    __syncthreads();
    const int cnt = cnt_s;

    if (t < 256) {   // snf[t] = sum_winners w_n * node_f[n, t]
        float s = 0.f;
        const float* base = node_f + (size_t)(b * NPB) * 256 + t;
        for (int i = 0; i < cnt; ++i) {
            int n = idx_s[i];
            s += w_s[n] * base[(size_t)n * 256];
        }
        snf_s[t] = s;
    } else {         // rj partials (4 groups x 64 j), in parallel with snf
        int j = (t - 256) & 63, g = (t - 256) >> 6;
        float mu = j * MU_STEP;
        float r = 0.f;
        for (int i = g; i < cnt; i += 4) {
            int n = idx_s[i];
            float uu = (d10_s[n] - mu) * INV_SIG;
            r += w_s[n] * __expf(-uu * uu);
        }
        red[t - 256] = r;
    }
    __syncthreads();
    if (t < 64) rj_s[t] = red[t] + red[t + 64] + red[t + 128] + red[t + 192];
    __syncthreads();

    float x = 0.f;
    if (t < 256) {
        float u = 0.f;
        for (int c = 0; c < 256; c += 8) {
            float k8[8];
#pragma unroll
            for (int q = 0; q < 8; ++q) k8[q] = KT[(size_t)(c + q) * 256 + t];
#pragma unroll
            for (int q = 0; q < 8; ++q) u = fmaf(k8[q], snf_s[c + q], u);
        }
        float ee = 0.f;
        for (int j = 0; j < 64; j += 8) {
            float k8[8];
#pragma unroll
            for (int q = 0; q < 8; ++q) k8[q] = KT[(size_t)(256 + j + q) * 256 + t];
#pragma unroll
            for (int q = 0; q < 8; ++q) ee = fmaf(k8[q], rj_s[j + q], ee);
        }
        x = af_s[t] + (u + ee) * inv + bkv[256 + t];
    }

    float mean = block_sum512(x, red8, t) * (1.0f / 256.0f);
    float xc   = (t < 256) ? (x - mean) : 0.f;
    float var  = block_sum512(xc * xc, red8, t) * (1.0f / 256.0f);
    if (t < 256)
        af_s[t] = xc * rsqrtf(var + 1e-5f) * ln1_g[t] + ln1_b[t];   // af1 in LDS
    __syncthreads();

    // ---- MLP L1: m1[t] = relu(b1[t] + sum_c af1[c]*W1T[c][t]) ----
    {
        float acc = b1[t];
        const float* w = W1T + t;
        for (int k = 0; k < 256; k += 8) {
            float w8[8];
#pragma unroll
            for (int u = 0; u < 8; ++u) w8[u] = w[(size_t)(k + u) * 512];
#pragma unroll
            for (int u = 0; u < 8; ++u) acc = fmaf(af_s[k + u], w8[u], acc);
        }
        m1_s[t] = fmaxf(acc, 0.f);
    }
    __syncthreads();

    // ---- MLP L2: m2[t] = relu(b2[t] + sum_k m1[k]*W2T[k][t]) ----
    {
        float acc = b2[t];
        const float* w = W2T + t;
        for (int k = 0; k < 512; k += 8) {
            float w8[8];
#pragma unroll
            for (int u = 0; u < 8; ++u) w8[u] = w[(size_t)(k + u) * 512];
#pragma unroll
            for (int u = 0; u < 8; ++u) acc = fmaf(m1_s[k + u], w8[u], acc);
        }
        m2_s[t] = fmaxf(acc, 0.f);
    }
    __syncthreads();

    // ---- MLP L3 split-k halves: y[th] = b3 + sum_k m2[k]*W3T[k][th] ----
    const int th = t & 255, kh = t >> 8;
    {
        float p = (kh == 0) ? b3[th] : 0.f;
        const float* w = W3T + th;
        const int kb = kh * 256;
        for (int k = 0; k < 256; k += 8) {
            float w8[8];
#pragma unroll
            for (int u = 0; u < 8; ++u) w8[u] = w[(size_t)(kb + k + u) * 256];
#pragma unroll
            for (int u = 0; u < 8; ++u) p = fmaf(m2_s[kb + k + u], w8[u], p);
        }
        m1_s[t] = p;                     // m1_s dead: reuse for partial combine
    }
    __syncthreads();

    // ---- residual + LN2 -> out ----
    float y = 0.f, gv = 0.f, bv2 = 0.f;
    if (kh == 0) {
        y = m1_s[th] + m1_s[256 + th] + af_s[th];
        gv = g2[th]; bv2 = bb2[th];
    }
    float s2 = block_sum512((kh == 0) ? y : 0.f, red8, t);
    float mn = s2 * (1.0f / 256.0f);
    float yc = (kh == 0) ? (y - mn) : 0.f;
    float vr = block_sum512(yc * yc, red8, t) * (1.0f / 256.0f);
    if (kh == 0)
        out[(size_t)a * 256 + th] = yc * rsqrtf(vr + 1e-5f) * gv + bv2;
}

// ---------------------------------------------------------------------------
extern "C" void kernel_launch(void* const* d_in, const int* in_sizes, int n_in,
                              void* d_out, int out_size, void* d_ws, size_t ws_size,
                              hipStream_t stream)
{
    const float* anchor_x  = (const float*)d_in[0];
    const float* node_x    = (const float*)d_in[1];
    const float* anchor_f  = (const float*)d_in[2];
    const float* node_f    = (const float*)d_in[3];
    const float* node_mask = (const float*)d_in[6];
    const float* Wq        = (const float*)d_in[7];
    const float* bq        = (const float*)d_in[8];
    const float* Wkv       = (const float*)d_in[9];
    const float* bkv       = (const float*)d_in[10];
    const float* ln1_g     = (const float*)d_in[11];
    const float* ln1_b     = (const float*)d_in[12];
    const float* W1        = (const float*)d_in[13];
    const float* b1        = (const float*)d_in[14];
    const float* W2        = (const float*)d_in[15];
    const float* b2        = (const float*)d_in[16];
    const float* W3        = (const float*)d_in[17];
    const float* b3        = (const float*)d_in[18];
    const float* ln2_g     = (const float*)d_in[19];
    const float* ln2_b     = (const float*)d_in[20];

    float* ws   = (float*)d_ws;
    float* G    = ws + OFF_G;
    float* KT   = ws + OFF_KT;
    float* W1T  = ws + OFF_W1T;
    float* W2T  = ws + OFF_W2T;
    float* W3T  = ws + OFF_W3T;

    prep_weights<<<178, 256, 0, stream>>>(Wq, bq, Wkv, bkv, W1, W2, W3,
                                          G, KT, W1T, W2T, W3T);

    fused_all<<<NA, 512, 0, stream>>>(anchor_x, node_x, anchor_f, node_f,
                                      node_mask, G, KT, bkv, ln1_g, ln1_b,
                                      W1T, b1, W2T, b2, W3T, b3,
                                      ln2_g, ln2_b, (float*)d_out);
}

// Round 13
// 207.530 us; speedup vs baseline: 1.1186x; 1.0468x over previous
//
#include <hip/hip_runtime.h>

// Problem constants (fixed by reference)
#define H    256
#define HE   64
#define NPB  512         // nodes per batch
#define NA   512         // total anchors (8 batches * 64)
#define MU_STEP (20.0f / 63.0f)
#define INV_SIG 3.2f     // 1/0.3125
#define G_LD 384
#define NF_LD4 65        // LDS row stride in float4 (260 floats)

// workspace float offsets
#define OFF_G    0          // 320x384
#define OFF_KT   122880     // [c][vrow] 320*256
#define OFF_W1T  204800     // 256*512
#define OFF_W2T  335872     // 512*512
#define OFF_W3T  598016     // 512*256

// ---------------------------------------------------------------------------
__device__ __forceinline__ float wave_sum(float v) {
#pragma unroll
    for (int o = 32; o; o >>= 1) v += __shfl_xor(v, o, 64);
    return v;
}
__device__ __forceinline__ float wave_max(float v) {
#pragma unroll
    for (int o = 32; o; o >>= 1) v = fmaxf(v, __shfl_xor(v, o, 64));
    return v;
}
__device__ __forceinline__ float block_sum512(float v, float* red8, int t) {
    v = wave_sum(v);
    if ((t & 63) == 0) red8[t >> 6] = v;
    __syncthreads();
    v = red8[0] + red8[1] + red8[2] + red8[3]
      + red8[4] + red8[5] + red8[6] + red8[7];
    __syncthreads();
    return v;
}

// ---------------------------------------------------------------------------
// K1: weights prep (first dispatch — absorbs the fixed ~50us first-slot ramp).
//  blocks 0..147: transposes (W1T, W2T, W3T, KT); 148..177: G GEMM.
//  G[j][n] = sum_c [Wq|bq][c][j] * [Wkv|bkv_k][c][n]; row 256 = bias row.
// ---------------------------------------------------------------------------
__global__ void __launch_bounds__(256) prep_weights(
    const float* __restrict__ Wq,  const float* __restrict__ bq,
    const float* __restrict__ Wkv, const float* __restrict__ bkv,
    const float* __restrict__ W1, const float* __restrict__ W2,
    const float* __restrict__ W3,
    float* __restrict__ G, float* __restrict__ KT,
    float* __restrict__ W1T, float* __restrict__ W2T, float* __restrict__ W3T)
{
    __shared__ float lds[8192];              // 32 KB
    const int bid = blockIdx.x, t = threadIdx.x;

    if (bid < 148) {
        float (*tile)[65] = (float(*)[65])lds;
        const float* src; float* dst; int C, Rd, tr, tc;
        if (bid < 32)       { src = W1; dst = W1T; C = 256; Rd = 512; tr = bid >> 2; tc = bid & 3; }
        else if (bid < 96)  { int ti = bid - 32; src = W2; dst = W2T; C = 512; Rd = 512; tr = ti >> 3; tc = ti & 7; }
        else if (bid < 128) { int ti = bid - 96; src = W3; dst = W3T; C = 512; Rd = 256; tr = ti >> 3; tc = ti & 7; }
        else                { int ti = bid - 128; src = Wkv + 256 * 320; dst = KT; C = 320; Rd = 256; tr = ti / 5; tc = ti % 5; }
        const int lane = t & 63, rg = t >> 6;
#pragma unroll
        for (int i = 0; i < 16; ++i) {
            int r = rg * 16 + i;
            tile[r][lane] = src[(size_t)(tr * 64 + r) * C + tc * 64 + lane];
        }
        __syncthreads();
#pragma unroll
        for (int i = 0; i < 16; ++i) {
            int r = rg * 16 + i;
            dst[(size_t)(tc * 64 + r) * Rd + tr * 64 + lane] = tile[lane][r];
        }
    } else {
        float* Als = lds;            // [c][j] 64x64
        float* Bls = lds + 4096;     // [c][n] 64x64
        const int gb = bid - 148;    // 0..29  (5 j-tiles x 6 n-tiles)
        const int mt = gb / 6, nt = gb - mt * 6;
        const int m0 = mt * 64, n0 = nt * 64;
        const int nq = t & 15, mq = t >> 4;
        float acc[4][4];
#pragma unroll
        for (int i = 0; i < 4; ++i)
#pragma unroll
            for (int k = 0; k < 4; ++k) acc[i][k] = 0.f;
        for (int c0 = 0; c0 < 256; c0 += 64) {
            __syncthreads();
            for (int idx = t; idx < 4096; idx += 256) {
                int cl = idx >> 6, el = idx & 63;
                int c = c0 + cl;
                int j = m0 + el;
                Als[idx] = (j < 256) ? Wq[(size_t)c * 256 + j] : (j == 256 ? bq[c] : 0.f);
                int n = n0 + el;
                Bls[idx] = (n < 320) ? Wkv[(size_t)c * 320 + n] : (n == 320 ? bkv[c] : 0.f);
            }
            __syncthreads();
#pragma unroll 4
            for (int cl = 0; cl < 64; ++cl) {
                const float* ar = Als + cl * 64 + mq * 4;
                const float* br = Bls + cl * 64 + nq * 4;
#pragma unroll
                for (int i = 0; i < 4; ++i)
#pragma unroll
                    for (int k = 0; k < 4; ++k)
                        acc[i][k] = fmaf(ar[i], br[k], acc[i][k]);
            }
        }
#pragma unroll
        for (int i = 0; i < 4; ++i) {
            int j = m0 + mq * 4 + i;
            float* gr = G + (size_t)j * G_LD + n0 + nq * 4;
            gr[0] = acc[i][0]; gr[1] = acc[i][1];
            gr[2] = acc[i][2]; gr[3] = acc[i][3];
        }
    }
}

// ---------------------------------------------------------------------------
// K2: everything, 2 anchors per block. 256 blocks x 512 threads.
//  aA = (bid&7)*64 + 2*(bid>>3), aB = aA+1 (XCD-pinned batch).
//  A: d10(both)/mask; B: [qW|qe|qbk] per half; C: logits (32 dbuf tiles, one
//  staged tile serves both anchors, q-frags in regs); D: half-block-per-anchor
//  softmax+winners+snf/rj+upd+LN1; MLP 2-anchor (1 weight load -> 2 FMA) +LN2.
// ---------------------------------------------------------------------------
__global__ void __launch_bounds__(512) fused_all(
    const float* __restrict__ anchor_x, const float* __restrict__ node_x,
    const float* __restrict__ anchor_f, const float* __restrict__ node_f,
    const float* __restrict__ node_mask,
    const float* __restrict__ G, const float* __restrict__ KT,
    const float* __restrict__ bkv,
    const float* __restrict__ ln1_g, const float* __restrict__ ln1_b,
    const float* __restrict__ W1T, const float* __restrict__ b1,
    const float* __restrict__ W2T, const float* __restrict__ b2,
    const float* __restrict__ W3T, const float* __restrict__ b3,
    const float* __restrict__ g2,  const float* __restrict__ bb2,
    float* __restrict__ out)
{
    const int bid = blockIdx.x;
    const int b  = bid & 7;                  // batch -> XCD
    const int pr = bid >> 3;                 // anchor pair 0..31
    const int aA = b * 64 + 2 * pr;
    const int aB = aA + 1;
    const int t  = threadIdx.x;
    const int th = t & 255, h = t >> 8;      // half-block anchor id

    __shared__ __align__(16) float nf_s[2][16 * NF_LD4 * 4];  // 33.3 KB (MLP reuses)
    __shared__ __align__(16) float qWe_s[2][324];  // per anchor: qW|qe|qbk
    __shared__ float af_s[2][256];           // anchor_f, later af1
    __shared__ float d10_s[2][NPB];
    __shared__ float mf_s[NPB];
    __shared__ float lg_s[2][NPB];
    __shared__ float w_s[2][NPB];
    __shared__ float snf_s[2][256], rj_s[2][64];
    __shared__ float red[512], red8[8];
    __shared__ int   idx_s[2][NPB];
    __shared__ int   cnt_s[2];

    if (t < 256) af_s[0][t]  = anchor_f[(size_t)aA * 256 + t];
    else         af_s[1][th] = anchor_f[(size_t)aB * 256 + th];
    if (t < 2) cnt_s[t] = 0;

    // Phase A: d10 for both anchors + mask factor, one node per thread
    {
        float axA0 = anchor_x[3 * aA], axA1 = anchor_x[3 * aA + 1], axA2 = anchor_x[3 * aA + 2];
        float axB0 = anchor_x[3 * aB], axB1 = anchor_x[3 * aB + 1], axB2 = anchor_x[3 * aB + 2];
        int ng = b * NPB + t;
        float nx0 = node_x[3 * ng], nx1 = node_x[3 * ng + 1], nx2 = node_x[3 * ng + 2];
        float dx = axA0 - nx0 + 1e-8f, dy = axA1 - nx1 + 1e-8f, dz = axA2 - nx2 + 1e-8f;
        d10_s[0][t] = sqrtf(dx * dx + dy * dy + dz * dz) * 0.1f;
        dx = axB0 - nx0 + 1e-8f; dy = axB1 - nx1 + 1e-8f; dz = axB2 - nx2 + 1e-8f;
        d10_s[1][t] = sqrtf(dx * dx + dy * dy + dz * dz) * 0.1f;
        mf_s[t] = (node_mask[ng] - 1.0f) * 1000000.0f;
    }
    __syncthreads();   // af_s, cnt_s ready

    // preload tile 0 (16 nodes x 64 float4; 2 regs/thread)
    const float4* src0 = (const float4*)(node_f + (size_t)(b * NPB) * 256);
    float4 rA = src0[t], rB = src0[t + 512];

    // Phase B: column th (and 256+th if th<65) of [qW|qe|qbk] for anchor h
    {
        const float* af = af_s[h];
        float acc = G[(size_t)256 * G_LD + th];
        for (int c = 0; c < 256; c += 8) {
            float g8[8];
#pragma unroll
            for (int u = 0; u < 8; ++u) g8[u] = G[(size_t)(c + u) * G_LD + th];
#pragma unroll
            for (int u = 0; u < 8; ++u) acc = fmaf(af[c + u], g8[u], acc);
        }
        qWe_s[h][th] = acc;
        if (th < 65) {
            int col = 256 + th;
            float acc2 = G[(size_t)256 * G_LD + col];
            for (int c = 0; c < 256; c += 8) {
                float g8[8];
#pragma unroll
                for (int u = 0; u < 8; ++u) g8[u] = G[(size_t)(c + u) * G_LD + col];
#pragma unroll
                for (int u = 0; u < 8; ++u) acc2 = fmaf(af[c + u], g8[u], acc2);
            }
            qWe_s[h][col] = acc2;
        }
    }

    // store tile 0 (padded: float4 idx = row*65 + col)
    const int dA = (t >> 6) * NF_LD4 + (t & 63);
    const int dB = ((t >> 6) + 8) * NF_LD4 + (t & 63);
    {
        float4* dst = (float4*)(nf_s[0]);
        dst[dA] = rA; dst[dB] = rB;
    }
    __syncthreads();   // qWe_s + tile 0 ready

    const int n16 = t >> 5, kc = t & 31;
    // tile-invariant query fragments -> registers
    const float4* qwA4 = (const float4*)qWe_s[0];
    const float4* qwB4 = (const float4*)qWe_s[1];
    const float4 q0A = qwA4[2 * kc], q1A = qwA4[2 * kc + 1];
    const float4 q0B = qwB4[2 * kc], q1B = qwB4[2 * kc + 1];
    const float qeA0 = qWe_s[0][256 + 2 * kc], qeA1 = qWe_s[0][257 + 2 * kc];
    const float qeB0 = qWe_s[1][256 + 2 * kc], qeB1 = qWe_s[1][257 + 2 * kc];
    const float qbkA = qWe_s[0][320], qbkB = qWe_s[1][320];
    const float mu0 = (2 * kc) * MU_STEP, mu1 = (2 * kc + 1) * MU_STEP;

    // ---- Phase C: logits for both anchors, 32 double-buffered tiles ----
    for (int tile = 0; tile < 32; ++tile) {
        if (tile < 31) {
            const float4* s2 = (const float4*)(node_f + (size_t)(b * NPB + (tile + 1) * 16) * 256);
            rA = s2[t]; rB = s2[t + 512];
        }

        const float4* nf4 = (const float4*)(nf_s[tile & 1]) + n16 * NF_LD4;
        float4 f0 = nf4[2 * kc], f1 = nf4[2 * kc + 1];
        float sA = q0A.x * f0.x + q0A.y * f0.y + q0A.z * f0.z + q0A.w * f0.w
                 + q1A.x * f1.x + q1A.y * f1.y + q1A.z * f1.z + q1A.w * f1.w;
        float sB = q0B.x * f0.x + q0B.y * f0.y + q0B.z * f0.z + q0B.w * f0.w
                 + q1B.x * f1.x + q1B.y * f1.y + q1B.z * f1.z + q1B.w * f1.w;

        const int n = tile * 16 + n16;
        const float dA10 = d10_s[0][n], dB10 = d10_s[1][n];
        {
            float u = (dA10 - mu0) * INV_SIG; sA = fmaf(qeA0, __expf(-u * u), sA);
            u = (dA10 - mu1) * INV_SIG;       sA = fmaf(qeA1, __expf(-u * u), sA);
            u = (dB10 - mu0) * INV_SIG;       sB = fmaf(qeB0, __expf(-u * u), sB);
            u = (dB10 - mu1) * INV_SIG;       sB = fmaf(qeB1, __expf(-u * u), sB);
        }
#pragma unroll
        for (int o = 1; o < 32; o <<= 1) {
            sA += __shfl_xor(sA, o, 64);
            sB += __shfl_xor(sB, o, 64);
        }
        if (kc == 0) {
            lg_s[0][n] = (sA + qbkA) * mf_s[n];
            lg_s[1][n] = (sB + qbkB) * mf_s[n];
        }

        if (tile < 31) {
            float4* dst = (float4*)(nf_s[(tile + 1) & 1]);
            dst[dA] = rA; dst[dB] = rB;
        }
        __syncthreads();
    }

    // ---- Phase D: per-half softmax + winners + snf/rj + upd + LN1 ----
    float lg0 = lg_s[h][th], lg1 = lg_s[h][th + 256];
    {
        float m = wave_max(fmaxf(lg0, lg1));
        if ((t & 63) == 0) red8[t >> 6] = m;
    }
    __syncthreads();
    float gm = fmaxf(fmaxf(red8[4 * h], red8[4 * h + 1]),
                     fmaxf(red8[4 * h + 2], red8[4 * h + 3]));
    __syncthreads();
    float e0 = __expf(lg0 - gm), e1 = __expf(lg1 - gm);
    w_s[h][th] = e0; w_s[h][th + 256] = e1;
    {
        float sm = wave_sum(e0 + e1);
        if ((t & 63) == 0) red8[t >> 6] = sm;
    }
    __syncthreads();
    float inv = 1.0f / (red8[4 * h] + red8[4 * h + 1] + red8[4 * h + 2] + red8[4 * h + 3]);

    if (e0 > 0.f) { int p = atomicAdd(&cnt_s[h], 1); idx_s[h][p] = th; }
    if (e1 > 0.f) { int p = atomicAdd(&cnt_s[h], 1); idx_s[h][p] = th + 256; }
    __syncthreads();
    const int cnt = cnt_s[h];

    {   // snf[h][th] = sum_winners w_n * node_f[n, th]
        float s = 0.f;
        const float* base = node_f + (size_t)(b * NPB) * 256 + th;
        for (int i = 0; i < cnt; ++i) {
            int n = idx_s[h][i];
            s += w_s[h][n] * base[(size_t)n * 256];
        }
        snf_s[h][th] = s;
    }
    {   // rj partials: per half, j = th&63, group = th>>6
        int j = th & 63, g = th >> 6;
        float mu = j * MU_STEP;
        float r = 0.f;
        for (int i = g; i < cnt; i += 4) {
            int n = idx_s[h][i];
            float uu = (d10_s[h][n] - mu) * INV_SIG;
            r += w_s[h][n] * __expf(-uu * uu);
        }
        red[t] = r;
    }
    __syncthreads();
    if (th < 64)
        rj_s[h][th] = red[h * 256 + th] + red[h * 256 + th + 64]
                    + red[h * 256 + th + 128] + red[h * 256 + th + 192];
    __syncthreads();

    float x;
    {   // upd: coalesced KT (both halves hit same addresses -> L1-hot)
        float u = 0.f;
        for (int c = 0; c < 256; c += 8) {
            float k8[8];
#pragma unroll
            for (int q = 0; q < 8; ++q) k8[q] = KT[(size_t)(c + q) * 256 + th];
#pragma unroll
            for (int q = 0; q < 8; ++q) u = fmaf(k8[q], snf_s[h][c + q], u);
        }
        float ee = 0.f;
        for (int j = 0; j < 64; j += 8) {
            float k8[8];
#pragma unroll
            for (int q = 0; q < 8; ++q) k8[q] = KT[(size_t)(256 + j + q) * 256 + th];
#pragma unroll
            for (int q = 0; q < 8; ++q) ee = fmaf(k8[q], rj_s[h][j + q], ee);
        }
        x = af_s[h][th] + (u + ee) * inv + bkv[256 + th];
    }

    // LN1 per half
    {
        float s1 = wave_sum(x);
        if ((t & 63) == 0) red8[t >> 6] = s1;
    }
    __syncthreads();
    float mean = (red8[4 * h] + red8[4 * h + 1] + red8[4 * h + 2] + red8[4 * h + 3]) * (1.0f / 256.0f);
    __syncthreads();
    float xc = x - mean;
    {
        float v1 = wave_sum(xc * xc);
        if ((t & 63) == 0) red8[t >> 6] = v1;
    }
    __syncthreads();
    float var = (red8[4 * h] + red8[4 * h + 1] + red8[4 * h + 2] + red8[4 * h + 3]) * (1.0f / 256.0f);
    __syncthreads();
    af_s[h][th] = xc * rsqrtf(var + 1e-5f) * ln1_g[th] + ln1_b[th];   // af1
    __syncthreads();

    // ---- MLP (m1/m2 aliased into dead nf_s): 1 weight load -> 2 FMA ----
    float* mlp = (float*)nf_s;   // [0..511] m1A, [512..1023] m1B,
                                 // [1024..1535] m2A, [1536..2047] m2B
    {
        float accA = b1[t], accB = accA;
        const float* w = W1T + t;
        for (int k = 0; k < 256; k += 8) {
            float w8[8];
#pragma unroll
            for (int u = 0; u < 8; ++u) w8[u] = w[(size_t)(k + u) * 512];
#pragma unroll
            for (int u = 0; u < 8; ++u) {
                accA = fmaf(af_s[0][k + u], w8[u], accA);
                accB = fmaf(af_s[1][k + u], w8[u], accB);
            }
        }
        mlp[t]       = fmaxf(accA, 0.f);
        mlp[512 + t] = fmaxf(accB, 0.f);
    }
    __syncthreads();

    {
        float accA = b2[t], accB = accA;
        const float* w = W2T + t;
        for (int k = 0; k < 512; k += 8) {
            float w8[8];
#pragma unroll
            for (int u = 0; u < 8; ++u) w8[u] = w[(size_t)(k + u) * 512];
#pragma unroll
            for (int u = 0; u < 8; ++u) {
                accA = fmaf(mlp[k + u],       w8[u], accA);
                accB = fmaf(mlp[512 + k + u], w8[u], accB);
            }
        }
        mlp[1024 + t] = fmaxf(accA, 0.f);
        mlp[1536 + t] = fmaxf(accB, 0.f);
    }
    __syncthreads();

    // L3 split-k halves: partials for both anchors
    const int kh = t >> 8;          // th already defined
    float pA, pB;
    {
        float bv = (kh == 0) ? b3[th] : 0.f;
        pA = bv; pB = bv;
        const float* w = W3T + th;
        const int kb = kh * 256;
        for (int k = 0; k < 256; k += 8) {
            float w8[8];
#pragma unroll
            for (int u = 0; u < 8; ++u) w8[u] = w[(size_t)(kb + k + u) * 256];
#pragma unroll
            for (int u = 0; u < 8; ++u) {
                pA = fmaf(mlp[1024 + kb + k + u], w8[u], pA);
                pB = fmaf(mlp[1536 + kb + k + u], w8[u], pB);
            }
        }
    }
    __syncthreads();                 // m1 region reads done
    mlp[t] = pA; mlp[512 + t] = pB;  // reuse m1 region for partial combine
    __syncthreads();

    // ---- residual + LN2 -> out (both anchors) ----
    float yA = 0.f, yB = 0.f, gv = 0.f, bv2 = 0.f;
    if (kh == 0) {
        yA = mlp[th] + mlp[256 + th] + af_s[0][th];
        yB = mlp[512 + th] + mlp[512 + 256 + th] + af_s[1][th];
        gv = g2[th]; bv2 = bb2[th];
    }
    {
        float s  = block_sum512((kh == 0) ? yA : 0.f, red8, t);
        float mn = s * (1.0f / 256.0f);
        float yc = (kh == 0) ? (yA - mn) : 0.f;
        float vr = block_sum512(yc * yc, red8, t) * (1.0f / 256.0f);
        if (kh == 0)
            out[(size_t)aA * 256 + th] = yc * rsqrtf(vr + 1e-5f) * gv + bv2;
    }
    {
        float s  = block_sum512((kh == 0) ? yB : 0.f, red8, t);
        float mn = s * (1.0f / 256.0f);
        float yc = (kh == 0) ? (yB - mn) : 0.f;
        float vr = block_sum512(yc * yc, red8, t) * (1.0f / 256.0f);
        if (kh == 0)
            out[(size_t)aB * 256 + th] = yc * rsqrtf(vr + 1e-5f) * gv + bv2;
    }
}

// ---------------------------------------------------------------------------
extern "C" void kernel_launch(void* const* d_in, const int* in_sizes, int n_in,
                              void* d_out, int out_size, void* d_ws, size_t ws_size,
                              hipStream_t stream)
{
    const float* anchor_x  = (const float*)d_in[0];
    const float* node_x    = (const float*)d_in[1];
    const float* anchor_f  = (const float*)d_in[2];
    const float* node_f    = (const float*)d_in[3];
    const float* node_mask = (const float*)d_in[6];
    const float* Wq        = (const float*)d_in[7];
    const float* bq        = (const float*)d_in[8];
    const float* Wkv       = (const float*)d_in[9];
    const float* bkv       = (const float*)d_in[10];
    const float* ln1_g     = (const float*)d_in[11];
    const float* ln1_b     = (const float*)d_in[12];
    const float* W1        = (const float*)d_in[13];
    const float* b1        = (const float*)d_in[14];
    const float* W2        = (const float*)d_in[15];
    const float* b2        = (const float*)d_in[16];
    const float* W3        = (const float*)d_in[17];
    const float* b3        = (const float*)d_in[18];
    const float* ln2_g     = (const float*)d_in[19];
    const float* ln2_b     = (const float*)d_in[20];

    float* ws   = (float*)d_ws;
    float* G    = ws + OFF_G;
    float* KT   = ws + OFF_KT;
    float* W1T  = ws + OFF_W1T;
    float* W2T  = ws + OFF_W2T;
    float* W3T  = ws + OFF_W3T;

    prep_weights<<<178, 256, 0, stream>>>(Wq, bq, Wkv, bkv, W1, W2, W3,
                                          G, KT, W1T, W2T, W3T);

    fused_all<<<256, 512, 0, stream>>>(anchor_x, node_x, anchor_f, node_f,
                                       node_mask, G, KT, bkv, ln1_g, ln1_b,
                                       W1T, b1, W2T, b2, W3T, b3,
                                       ln2_g, ln2_b, (float*)d_out);
}

// Round 14
// 172.947 us; speedup vs baseline: 1.3423x; 1.2000x over previous
//
#include <hip/hip_runtime.h>

// Problem constants (fixed by reference)
#define H    256
#define HE   64
#define NPB  512         // nodes per batch
#define NA   512         // total anchors (8 batches * 64)
#define MU_STEP (20.0f / 63.0f)
#define INV_SIG 3.2f     // 1/0.3125
#define NF_LD4 65        // LDS row stride in float4 (260 floats)

// ---------------------------------------------------------------------------
__device__ __forceinline__ float wave_sum(float v) {
#pragma unroll
    for (int o = 32; o; o >>= 1) v += __shfl_xor(v, o, 64);
    return v;
}
__device__ __forceinline__ float wave_max(float v) {
#pragma unroll
    for (int o = 32; o; o >>= 1) v = fmaxf(v, __shfl_xor(v, o, 64));
    return v;
}
__device__ __forceinline__ float block_sum512(float v, float* red8, int t) {
    v = wave_sum(v);
    if ((t & 63) == 0) red8[t >> 6] = v;
    __syncthreads();
    v = red8[0] + red8[1] + red8[2] + red8[3]
      + red8[4] + red8[5] + red8[6] + red8[7];
    __syncthreads();
    return v;
}

// ---------------------------------------------------------------------------
// Single kernel: everything, 2 anchors per block, raw weights (no prep).
// 256 blocks x 512 threads. aA=(bid&7)*64+2*(bid>>3), aB=aA+1 (XCD-pinned).
// Wave-GEMV pattern: wave computes 4 outputs in parallel (lane>>4 = output,
// lane&15 = k-chunk), loads 4x64B segments, 4-shuffle reduce.
// ---------------------------------------------------------------------------
__global__ void __launch_bounds__(512) fused_all(
    const float* __restrict__ anchor_x, const float* __restrict__ node_x,
    const float* __restrict__ anchor_f, const float* __restrict__ node_f,
    const float* __restrict__ node_mask,
    const float* __restrict__ Wq,  const float* __restrict__ bq,
    const float* __restrict__ Wkv, const float* __restrict__ bkv,
    const float* __restrict__ ln1_g, const float* __restrict__ ln1_b,
    const float* __restrict__ W1, const float* __restrict__ b1,
    const float* __restrict__ W2, const float* __restrict__ b2,
    const float* __restrict__ W3, const float* __restrict__ b3,
    const float* __restrict__ g2,  const float* __restrict__ bb2,
    float* __restrict__ out)
{
    const int bid = blockIdx.x;
    const int b  = bid & 7;                  // batch -> XCD
    const int pr = bid >> 3;                 // anchor pair 0..31
    const int aA = b * 64 + 2 * pr;
    const int aB = aA + 1;
    const int t  = threadIdx.x;
    const int th = t & 255, h = t >> 8;      // half-block anchor id
    const int wv = t >> 6, l = t & 63;       // wave id, lane
    const int sub = l >> 4, kc16 = l & 15;   // wave-GEMV: output-sub, k-chunk

    __shared__ __align__(16) float nf_s[2][16 * NF_LD4 * 4];  // 33.3 KB; MLP reuse
    __shared__ __align__(16) float qWe_s[2][324];  // qW 0-255, qe 256-319
    __shared__ float q_s[2][256];
    __shared__ float af_s[2][256];           // anchor_f, later af1
    __shared__ float d10_s[2][NPB];
    __shared__ float mf_s[NPB];
    __shared__ float lg_s[2][NPB];
    __shared__ float w_s[2][NPB];
    __shared__ float snf_s[2][256], rj_s[2][64];
    __shared__ float red[512], red8[8];
    __shared__ int   idx_s[2][NPB];
    __shared__ int   cnt_s[2];

    if (t < 256) af_s[0][t]  = anchor_f[(size_t)aA * 256 + t];
    else         af_s[1][th] = anchor_f[(size_t)aB * 256 + th];
    if (t < 2) cnt_s[t] = 0;

    // Phase A: d10 for both anchors + mask factor, one node per thread
    {
        float axA0 = anchor_x[3 * aA], axA1 = anchor_x[3 * aA + 1], axA2 = anchor_x[3 * aA + 2];
        float axB0 = anchor_x[3 * aB], axB1 = anchor_x[3 * aB + 1], axB2 = anchor_x[3 * aB + 2];
        int ng = b * NPB + t;
        float nx0 = node_x[3 * ng], nx1 = node_x[3 * ng + 1], nx2 = node_x[3 * ng + 2];
        float dx = axA0 - nx0 + 1e-8f, dy = axA1 - nx1 + 1e-8f, dz = axA2 - nx2 + 1e-8f;
        d10_s[0][t] = sqrtf(dx * dx + dy * dy + dz * dz) * 0.1f;
        dx = axB0 - nx0 + 1e-8f; dy = axB1 - nx1 + 1e-8f; dz = axB2 - nx2 + 1e-8f;
        d10_s[1][t] = sqrtf(dx * dx + dy * dy + dz * dz) * 0.1f;
        mf_s[t] = (node_mask[ng] - 1.0f) * 1000000.0f;
    }
    __syncthreads();   // af_s, cnt_s ready

    // preload tile 0 (16 nodes x 64 float4; 2 regs/thread)
    const float4* src0 = (const float4*)(node_f + (size_t)(b * NPB) * 256);
    float4 rA = src0[t], rB = src0[t + 512];

    // ---- Phase B1: q[m] = bq[m] + Wq[m,:].af  (wave-GEMV, both anchors) ----
    for (int pass = 0; pass < 8; ++pass) {
        int m = pass * 32 + wv * 4 + sub;
        const float* wr = Wq + (size_t)m * 256 + kc16;
        float aAc = 0.f, aBc = 0.f;
        for (int u = 0; u < 16; u += 8) {
            float w8[8];
#pragma unroll
            for (int v = 0; v < 8; ++v) w8[v] = wr[(u + v) * 16];
#pragma unroll
            for (int v = 0; v < 8; ++v) {
                int c = kc16 + (u + v) * 16;
                aAc = fmaf(w8[v], af_s[0][c], aAc);
                aBc = fmaf(w8[v], af_s[1][c], aBc);
            }
        }
#pragma unroll
        for (int o = 8; o >= 1; o >>= 1) {
            aAc += __shfl_xor(aAc, o, 64);
            aBc += __shfl_xor(aBc, o, 64);
        }
        if (kc16 == 0) {
            float bv = bq[m];
            q_s[0][m] = aAc + bv;
            q_s[1][m] = aBc + bv;
        }
    }
    __syncthreads();   // q_s ready

    // ---- Phase B2: qW/qe column walk over raw Wkv rows 0..255 ----
    if (t < 320) {
        float aAc = 0.f, aBc = 0.f;
        for (int o = 0; o < 256; o += 8) {
            float w8[8];
#pragma unroll
            for (int u = 0; u < 8; ++u) w8[u] = Wkv[(size_t)(o + u) * 320 + t];
#pragma unroll
            for (int u = 0; u < 8; ++u) {
                aAc = fmaf(w8[u], q_s[0][o + u], aAc);
                aBc = fmaf(w8[u], q_s[1][o + u], aBc);
            }
        }
        qWe_s[0][t] = aAc;
        qWe_s[1][t] = aBc;
    }
    // store tile 0 (padded: float4 idx = row*65 + col)
    const int dA = (t >> 6) * NF_LD4 + (t & 63);
    const int dB = ((t >> 6) + 8) * NF_LD4 + (t & 63);
    {
        float4* dst = (float4*)(nf_s[0]);
        dst[dA] = rA; dst[dB] = rB;
    }
    // qbk via block reductions (their syncs publish qWe_s, q_s, tile 0)
    float qbkA = block_sum512((t < 256) ? q_s[0][t] * bkv[t] : 0.f, red8, t);
    float qbkB = block_sum512((t < 256) ? q_s[1][t] * bkv[t] : 0.f, red8, t);

    const int n16 = t >> 5, kc = t & 31;
    // tile-invariant query fragments -> registers
    const float4* qwA4 = (const float4*)qWe_s[0];
    const float4* qwB4 = (const float4*)qWe_s[1];
    const float4 q0A = qwA4[2 * kc], q1A = qwA4[2 * kc + 1];
    const float4 q0B = qwB4[2 * kc], q1B = qwB4[2 * kc + 1];
    const float qeA0 = qWe_s[0][256 + 2 * kc], qeA1 = qWe_s[0][257 + 2 * kc];
    const float qeB0 = qWe_s[1][256 + 2 * kc], qeB1 = qWe_s[1][257 + 2 * kc];
    const float mu0 = (2 * kc) * MU_STEP, mu1 = (2 * kc + 1) * MU_STEP;

    // ---- Phase C: logits for both anchors, 32 double-buffered tiles ----
    for (int tile = 0; tile < 32; ++tile) {
        if (tile < 31) {
            const float4* s2 = (const float4*)(node_f + (size_t)(b * NPB + (tile + 1) * 16) * 256);
            rA = s2[t]; rB = s2[t + 512];
        }

        const float4* nf4 = (const float4*)(nf_s[tile & 1]) + n16 * NF_LD4;
        float4 f0 = nf4[2 * kc], f1 = nf4[2 * kc + 1];
        float sA = q0A.x * f0.x + q0A.y * f0.y + q0A.z * f0.z + q0A.w * f0.w
                 + q1A.x * f1.x + q1A.y * f1.y + q1A.z * f1.z + q1A.w * f1.w;
        float sB = q0B.x * f0.x + q0B.y * f0.y + q0B.z * f0.z + q0B.w * f0.w
                 + q1B.x * f1.x + q1B.y * f1.y + q1B.z * f1.z + q1B.w * f1.w;

        const int n = tile * 16 + n16;
        const float dA10 = d10_s[0][n], dB10 = d10_s[1][n];
        {
            float u = (dA10 - mu0) * INV_SIG; sA = fmaf(qeA0, __expf(-u * u), sA);
            u = (dA10 - mu1) * INV_SIG;       sA = fmaf(qeA1, __expf(-u * u), sA);
            u = (dB10 - mu0) * INV_SIG;       sB = fmaf(qeB0, __expf(-u * u), sB);
            u = (dB10 - mu1) * INV_SIG;       sB = fmaf(qeB1, __expf(-u * u), sB);
        }
#pragma unroll
        for (int o = 1; o < 32; o <<= 1) {
            sA += __shfl_xor(sA, o, 64);
            sB += __shfl_xor(sB, o, 64);
        }
        if (kc == 0) {
            lg_s[0][n] = (sA + qbkA) * mf_s[n];
            lg_s[1][n] = (sB + qbkB) * mf_s[n];
        }

        if (tile < 31) {
            float4* dst = (float4*)(nf_s[(tile + 1) & 1]);
            dst[dA] = rA; dst[dB] = rB;
        }
        __syncthreads();
    }

    // ---- Phase D: per-half softmax + winners + snf/rj ----
    float lg0 = lg_s[h][th], lg1 = lg_s[h][th + 256];
    {
        float m = wave_max(fmaxf(lg0, lg1));
        if ((t & 63) == 0) red8[t >> 6] = m;
    }
    __syncthreads();
    float gm = fmaxf(fmaxf(red8[4 * h], red8[4 * h + 1]),
                     fmaxf(red8[4 * h + 2], red8[4 * h + 3]));
    __syncthreads();
    float e0 = __expf(lg0 - gm), e1 = __expf(lg1 - gm);
    w_s[h][th] = e0; w_s[h][th + 256] = e1;
    {
        float sm = wave_sum(e0 + e1);
        if ((t & 63) == 0) red8[t >> 6] = sm;
    }
    __syncthreads();
    float inv = 1.0f / (red8[4 * h] + red8[4 * h + 1] + red8[4 * h + 2] + red8[4 * h + 3]);

    if (e0 > 0.f) { int p = atomicAdd(&cnt_s[h], 1); idx_s[h][p] = th; }
    if (e1 > 0.f) { int p = atomicAdd(&cnt_s[h], 1); idx_s[h][p] = th + 256; }
    __syncthreads();
    const int cnt = cnt_s[h];

    {   // snf[h][th] = sum_winners w_n * node_f[n, th]
        float s = 0.f;
        const float* base = node_f + (size_t)(b * NPB) * 256 + th;
        for (int i = 0; i < cnt; ++i) {
            int n = idx_s[h][i];
            s += w_s[h][n] * base[(size_t)n * 256];
        }
        snf_s[h][th] = s;
    }
    {   // rj partials: per half, j = th&63, group = th>>6
        int j = th & 63, g = th >> 6;
        float mu = j * MU_STEP;
        float r = 0.f;
        for (int i = g; i < cnt; i += 4) {
            int n = idx_s[h][i];
            float uu = (d10_s[h][n] - mu) * INV_SIG;
            r += w_s[h][n] * __expf(-uu * uu);
        }
        red[t] = r;
    }
    __syncthreads();
    if (th < 64)
        rj_s[h][th] = red[h * 256 + th] + red[h * 256 + th + 64]
                    + red[h * 256 + th + 128] + red[h * 256 + th + 192];
    __syncthreads();

    // ---- upd via wave-GEMV over raw Wkv v-rows (K = 256 snf + 64 rj) ----
    for (int pass = 0; pass < 8; ++pass) {
        int m = pass * 32 + wv * 4 + sub;
        const float* wr = Wkv + (size_t)(256 + m) * 320 + kc16;
        float aAc = 0.f, aBc = 0.f;
        for (int u = 0; u < 16; u += 8) {
            float w8[8];
#pragma unroll
            for (int v = 0; v < 8; ++v) w8[v] = wr[(u + v) * 16];
#pragma unroll
            for (int v = 0; v < 8; ++v) {
                int c = kc16 + (u + v) * 16;
                aAc = fmaf(w8[v], snf_s[0][c], aAc);
                aBc = fmaf(w8[v], snf_s[1][c], aBc);
            }
        }
        {
            float w4r[4];
#pragma unroll
            for (int v = 0; v < 4; ++v) w4r[v] = wr[256 + v * 16];
#pragma unroll
            for (int v = 0; v < 4; ++v) {
                int j = kc16 + v * 16;
                aAc = fmaf(w4r[v], rj_s[0][j], aAc);
                aBc = fmaf(w4r[v], rj_s[1][j], aBc);
            }
        }
#pragma unroll
        for (int o = 8; o >= 1; o >>= 1) {
            aAc += __shfl_xor(aAc, o, 64);
            aBc += __shfl_xor(aBc, o, 64);
        }
        if (kc16 == 0) { red[m] = aAc; red[256 + m] = aBc; }
    }
    __syncthreads();

    // ---- residual + LN1 (per half) ----
    float x = af_s[h][th] + red[h * 256 + th] * inv + bkv[256 + th];
    {
        float s1 = wave_sum(x);
        if ((t & 63) == 0) red8[t >> 6] = s1;
    }
    __syncthreads();
    float mean = (red8[4 * h] + red8[4 * h + 1] + red8[4 * h + 2] + red8[4 * h + 3]) * (1.0f / 256.0f);
    __syncthreads();
    float xc = x - mean;
    {
        float v1 = wave_sum(xc * xc);
        if ((t & 63) == 0) red8[t >> 6] = v1;
    }
    __syncthreads();
    float var = (red8[4 * h] + red8[4 * h + 1] + red8[4 * h + 2] + red8[4 * h + 3]) * (1.0f / 256.0f);
    __syncthreads();
    af_s[h][th] = xc * rsqrtf(var + 1e-5f) * ln1_g[th] + ln1_b[th];   // af1
    __syncthreads();

    // ---- MLP (wave-GEMV over raw W1/W2/W3; m1/m2 in dead nf_s) ----
    float* mlp = (float*)nf_s;   // [0..511] m1A, [512..1023] m1B,
                                 // [1024..1535] m2A, [1536..2047] m2B
    // L1: 512 outputs, K=256
    for (int pass = 0; pass < 16; ++pass) {
        int m = pass * 32 + wv * 4 + sub;
        const float* wr = W1 + (size_t)m * 256 + kc16;
        float aAc = 0.f, aBc = 0.f;
        for (int u = 0; u < 16; u += 8) {
            float w8[8];
#pragma unroll
            for (int v = 0; v < 8; ++v) w8[v] = wr[(u + v) * 16];
#pragma unroll
            for (int v = 0; v < 8; ++v) {
                int c = kc16 + (u + v) * 16;
                aAc = fmaf(w8[v], af_s[0][c], aAc);
                aBc = fmaf(w8[v], af_s[1][c], aBc);
            }
        }
#pragma unroll
        for (int o = 8; o >= 1; o >>= 1) {
            aAc += __shfl_xor(aAc, o, 64);
            aBc += __shfl_xor(aBc, o, 64);
        }
        if (kc16 == 0) {
            float bv = b1[m];
            mlp[m]       = fmaxf(aAc + bv, 0.f);
            mlp[512 + m] = fmaxf(aBc + bv, 0.f);
        }
    }
    __syncthreads();

    // L2: 512 outputs, K=512
    for (int pass = 0; pass < 16; ++pass) {
        int m = pass * 32 + wv * 4 + sub;
        const float* wr = W2 + (size_t)m * 512 + kc16;
        float aAc = 0.f, aBc = 0.f;
        for (int u = 0; u < 32; u += 8) {
            float w8[8];
#pragma unroll
            for (int v = 0; v < 8; ++v) w8[v] = wr[(u + v) * 16];
#pragma unroll
            for (int v = 0; v < 8; ++v) {
                int c = kc16 + (u + v) * 16;
                aAc = fmaf(w8[v], mlp[c], aAc);
                aBc = fmaf(w8[v], mlp[512 + c], aBc);
            }
        }
#pragma unroll
        for (int o = 8; o >= 1; o >>= 1) {
            aAc += __shfl_xor(aAc, o, 64);
            aBc += __shfl_xor(aBc, o, 64);
        }
        if (kc16 == 0) {
            float bv = b2[m];
            mlp[1024 + m] = fmaxf(aAc + bv, 0.f);
            mlp[1536 + m] = fmaxf(aBc + bv, 0.f);
        }
    }
    __syncthreads();

    // L3: 256 outputs, K=512 -> y into red[]
    for (int pass = 0; pass < 8; ++pass) {
        int m = pass * 32 + wv * 4 + sub;
        const float* wr = W3 + (size_t)m * 512 + kc16;
        float aAc = 0.f, aBc = 0.f;
        for (int u = 0; u < 32; u += 8) {
            float w8[8];
#pragma unroll
            for (int v = 0; v < 8; ++v) w8[v] = wr[(u + v) * 16];
#pragma unroll
            for (int v = 0; v < 8; ++v) {
                int c = kc16 + (u + v) * 16;
                aAc = fmaf(w8[v], mlp[1024 + c], aAc);
                aBc = fmaf(w8[v], mlp[1536 + c], aBc);
            }
        }
#pragma unroll
        for (int o = 8; o >= 1; o >>= 1) {
            aAc += __shfl_xor(aAc, o, 64);
            aBc += __shfl_xor(aBc, o, 64);
        }
        if (kc16 == 0) {
            float bv = b3[m];
            red[m]       = aAc + bv;
            red[256 + m] = aBc + bv;
        }
    }
    __syncthreads();

    // ---- residual + LN2 -> out (both anchors) ----
    const int kh = t >> 8;
    float yA = 0.f, yB = 0.f, gv = 0.f, bv2 = 0.f;
    if (kh == 0) {
        yA = red[th] + af_s[0][th];
        yB = red[256 + th] + af_s[1][th];
        gv = g2[th]; bv2 = bb2[th];
    }
    {
        float s  = block_sum512((kh == 0) ? yA : 0.f, red8, t);
        float mn = s * (1.0f / 256.0f);
        float yc = (kh == 0) ? (yA - mn) : 0.f;
        float vr = block_sum512(yc * yc, red8, t) * (1.0f / 256.0f);
        if (kh == 0)
            out[(size_t)aA * 256 + th] = yc * rsqrtf(vr + 1e-5f) * gv + bv2;
    }
    {
        float s  = block_sum512((kh == 0) ? yB : 0.f, red8, t);
        float mn = s * (1.0f / 256.0f);
        float yc = (kh == 0) ? (yB - mn) : 0.f;
        float vr = block_sum512(yc * yc, red8, t) * (1.0f / 256.0f);
        if (kh == 0)
            out[(size_t)aB * 256 + th] = yc * rsqrtf(vr + 1e-5f) * gv + bv2;
    }
}

// ---------------------------------------------------------------------------
extern "C" void kernel_launch(void* const* d_in, const int* in_sizes, int n_in,
                              void* d_out, int out_size, void* d_ws, size_t ws_size,
                              hipStream_t stream)
{
    const float* anchor_x  = (const float*)d_in[0];
    const float* node_x    = (const float*)d_in[1];
    const float* anchor_f  = (const float*)d_in[2];
    const float* node_f    = (const float*)d_in[3];
    const float* node_mask = (const float*)d_in[6];
    const float* Wq        = (const float*)d_in[7];
    const float* bq        = (const float*)d_in[8];
    const float* Wkv       = (const float*)d_in[9];
    const float* bkv       = (const float*)d_in[10];
    const float* ln1_g     = (const float*)d_in[11];
    const float* ln1_b     = (const float*)d_in[12];
    const float* W1        = (const float*)d_in[13];
    const float* b1        = (const float*)d_in[14];
    const float* W2        = (const float*)d_in[15];
    const float* b2        = (const float*)d_in[16];
    const float* W3        = (const float*)d_in[17];
    const float* b3        = (const float*)d_in[18];
    const float* ln2_g     = (const float*)d_in[19];
    const float* ln2_b     = (const float*)d_in[20];

    fused_all<<<256, 512, 0, stream>>>(anchor_x, node_x, anchor_f, node_f,
                                       node_mask, Wq, bq, Wkv, bkv,
                                       ln1_g, ln1_b, W1, b1, W2, b2, W3, b3,
                                       ln2_g, ln2_b, (float*)d_out);
}

// Round 15
// 166.216 us; speedup vs baseline: 1.3967x; 1.0405x over previous
//
#include <hip/hip_runtime.h>

// Problem constants (fixed by reference)
#define H    256
#define HE   64
#define NPB  512         // nodes per batch
#define NA   512         // total anchors (8 batches * 64)
#define MU_STEP (20.0f / 63.0f)
#define INV_SIG 3.2f     // 1/0.3125

// ---------------------------------------------------------------------------
__device__ __forceinline__ float wave_sum(float v) {
#pragma unroll
    for (int o = 32; o; o >>= 1) v += __shfl_xor(v, o, 64);
    return v;
}
__device__ __forceinline__ float wave_max(float v) {
#pragma unroll
    for (int o = 32; o; o >>= 1) v = fmaxf(v, __shfl_xor(v, o, 64));
    return v;
}
__device__ __forceinline__ float block_sum1024(float v, float* red16, int t) {
    v = wave_sum(v);
    if ((t & 63) == 0) red16[t >> 6] = v;
    __syncthreads();
    v = 0.f;
#pragma unroll
    for (int i = 0; i < 16; ++i) v += red16[i];
    __syncthreads();
    return v;
}

// ---------------------------------------------------------------------------
// Single kernel: everything, 2 anchors per block, raw weights.
// 256 blocks x 1024 threads (16 waves/CU). aA=(bid&7)*64+2*(bid>>3), aB=aA+1.
// Phase C is barrier-free: each wave owns one node per pass, lane = one
// float4 of the row loaded straight from global (pipelined), 64-lane reduce.
// Wave-GEMVs: 16 waves x 4 outputs/pass (lane>>4 = output, lane&15 = k-chunk).
// ---------------------------------------------------------------------------
__global__ void __launch_bounds__(1024) fused_all(
    const float* __restrict__ anchor_x, const float* __restrict__ node_x,
    const float* __restrict__ anchor_f, const float* __restrict__ node_f,
    const float* __restrict__ node_mask,
    const float* __restrict__ Wq,  const float* __restrict__ bq,
    const float* __restrict__ Wkv, const float* __restrict__ bkv,
    const float* __restrict__ ln1_g, const float* __restrict__ ln1_b,
    const float* __restrict__ W1, const float* __restrict__ b1,
    const float* __restrict__ W2, const float* __restrict__ b2,
    const float* __restrict__ W3, const float* __restrict__ b3,
    const float* __restrict__ g2,  const float* __restrict__ bb2,
    float* __restrict__ out)
{
    const int bid = blockIdx.x;
    const int b  = bid & 7;                  // batch -> XCD
    const int pr = bid >> 3;                 // anchor pair 0..31
    const int aA = b * 64 + 2 * pr;
    const int aB = aA + 1;
    const int t  = threadIdx.x;              // 0..1023
    const int wv = t >> 6, l = t & 63;       // wave id (0..15), lane
    const int sub = l >> 4, kc16 = l & 15;   // wave-GEMV: output-sub, k-chunk

    __shared__ __align__(16) float qWe_s[2][324];  // qW 0-255, qe 256-319
    __shared__ float q_s[2][256];
    __shared__ float af_s[2][256];           // anchor_f, later af1
    __shared__ float d10_s[2][NPB];
    __shared__ float mf_s[NPB];
    __shared__ float lg_s[2][NPB];
    __shared__ float w_s[2][NPB];
    __shared__ float snf_s[2][256], rj_s[2][64];
    __shared__ float m1_s[2][512], m2_s[2][512];
    __shared__ float red[512], red16[16];
    __shared__ int   idx_s[2][NPB];
    __shared__ int   cnt_s[2];

    if (t < 256)       af_s[0][t]        = anchor_f[(size_t)aA * 256 + t];
    else if (t < 512)  af_s[1][t - 256]  = anchor_f[(size_t)aB * 256 + (t - 256)];
    if (t < 2) cnt_s[t] = 0;

    // Phase A: d10 for both anchors + mask factor, one node per thread (t<512)
    if (t < 512) {
        float axA0 = anchor_x[3 * aA], axA1 = anchor_x[3 * aA + 1], axA2 = anchor_x[3 * aA + 2];
        float axB0 = anchor_x[3 * aB], axB1 = anchor_x[3 * aB + 1], axB2 = anchor_x[3 * aB + 2];
        int ng = b * NPB + t;
        float nx0 = node_x[3 * ng], nx1 = node_x[3 * ng + 1], nx2 = node_x[3 * ng + 2];
        float dx = axA0 - nx0 + 1e-8f, dy = axA1 - nx1 + 1e-8f, dz = axA2 - nx2 + 1e-8f;
        d10_s[0][t] = sqrtf(dx * dx + dy * dy + dz * dz) * 0.1f;
        dx = axB0 - nx0 + 1e-8f; dy = axB1 - nx1 + 1e-8f; dz = axB2 - nx2 + 1e-8f;
        d10_s[1][t] = sqrtf(dx * dx + dy * dy + dz * dz) * 0.1f;
        mf_s[t] = (node_mask[ng] - 1.0f) * 1000000.0f;
    }
    __syncthreads();   // af_s, cnt_s, d10_s, mf_s ready

    // ---- Phase B1: q[m] = bq[m] + Wq[m,:].af  (wave-GEMV, 4 passes) ----
#pragma unroll
    for (int pass = 0; pass < 4; ++pass) {
        int m = pass * 64 + wv * 4 + sub;
        const float* wr = Wq + (size_t)m * 256 + kc16;
        float aAc = 0.f, aBc = 0.f;
        for (int u = 0; u < 16; u += 8) {
            float w8[8];
#pragma unroll
            for (int v = 0; v < 8; ++v) w8[v] = wr[(u + v) * 16];
#pragma unroll
            for (int v = 0; v < 8; ++v) {
                int c = kc16 + (u + v) * 16;
                aAc = fmaf(w8[v], af_s[0][c], aAc);
                aBc = fmaf(w8[v], af_s[1][c], aBc);
            }
        }
#pragma unroll
        for (int o = 8; o >= 1; o >>= 1) {
            aAc += __shfl_xor(aAc, o, 64);
            aBc += __shfl_xor(aBc, o, 64);
        }
        if (kc16 == 0) {
            float bv = bq[m];
            q_s[0][m] = aAc + bv;
            q_s[1][m] = aBc + bv;
        }
    }
    __syncthreads();   // q_s ready

    // ---- Phase B2: qW/qe column walk over raw Wkv rows 0..255 ----
    // threads 0..319: anchor A col t; threads 512..831: anchor B col t-512
    {
        int ha = -1, col = 0;
        if (t < 320)                   { ha = 0; col = t; }
        else if (t >= 512 && t < 832)  { ha = 1; col = t - 512; }
        if (ha >= 0) {
            const float* qs = q_s[ha];
            float acc = 0.f;
            for (int o = 0; o < 256; o += 8) {
                float w8[8];
#pragma unroll
                for (int u = 0; u < 8; ++u) w8[u] = Wkv[(size_t)(o + u) * 320 + col];
#pragma unroll
                for (int u = 0; u < 8; ++u) acc = fmaf(w8[u], qs[o + u], acc);
            }
            qWe_s[ha][col] = acc;
        }
    }
    // qbk via block reductions (their syncs publish qWe_s)
    float qbkA = block_sum1024((t < 256) ? q_s[0][t] * bkv[t] : 0.f, red16, t);
    float qbkB = block_sum1024((t < 256) ? q_s[1][t] * bkv[t] : 0.f, red16, t);

    // ---- Phase C: logits, barrier-free. wave wv owns nodes wv, wv+16, ... ----
    {
        const float4 qA = ((const float4*)qWe_s[0])[l];
        const float4 qB = ((const float4*)qWe_s[1])[l];
        const float qeA = qWe_s[0][256 + l], qeB = qWe_s[1][256 + l];
        const float muL = l * MU_STEP;
        const float4* nfb = (const float4*)(node_f + (size_t)(b * NPB) * 256);

        float4 f = nfb[(size_t)wv * 64 + l];
        for (int it = 0; it < 32; ++it) {
            const int n = wv + it * 16;
            float4 fn;
            if (it < 31) fn = nfb[(size_t)(n + 16) * 64 + l];

            float sA = qA.x * f.x + qA.y * f.y + qA.z * f.z + qA.w * f.w;
            float sB = qB.x * f.x + qB.y * f.y + qB.z * f.z + qB.w * f.w;
            float dA10 = d10_s[0][n], dB10 = d10_s[1][n];   // wave-uniform
            float u = (dA10 - muL) * INV_SIG; sA = fmaf(qeA, __expf(-u * u), sA);
            u = (dB10 - muL) * INV_SIG;       sB = fmaf(qeB, __expf(-u * u), sB);
#pragma unroll
            for (int o = 1; o < 64; o <<= 1) {
                sA += __shfl_xor(sA, o, 64);
                sB += __shfl_xor(sB, o, 64);
            }
            if (l == 0) {
                lg_s[0][n] = (sA + qbkA) * mf_s[n];
                lg_s[1][n] = (sB + qbkB) * mf_s[n];
            }
            f = fn;
        }
    }
    __syncthreads();

    // ---- Phase D: softmax (anchor h8 = t>>9, node n9 = t&511) ----
    const int h8 = t >> 9, n9 = t & 511;
    float lg = lg_s[h8][n9];
    {
        float m = wave_max(lg);
        if (l == 0) red16[wv] = m;
    }
    __syncthreads();
    float gmA = red16[0], gmB = red16[8];
#pragma unroll
    for (int i = 1; i < 8; ++i) { gmA = fmaxf(gmA, red16[i]); gmB = fmaxf(gmB, red16[8 + i]); }
    __syncthreads();
    float e = __expf(lg - (h8 ? gmB : gmA));
    w_s[h8][n9] = e;
    {
        float sm = wave_sum(e);
        if (l == 0) red16[wv] = sm;
    }
    __syncthreads();
    float smA = 0.f, smB = 0.f;
#pragma unroll
    for (int i = 0; i < 8; ++i) { smA += red16[i]; smB += red16[8 + i]; }
    const float invA = 1.0f / smA, invB = 1.0f / smB;
    if (e > 0.f) { int p = atomicAdd(&cnt_s[h8], 1); idx_s[h8][p] = n9; }
    __syncthreads();

    // ---- snf (t<512) || rj partials (t>=512), fully parallel ----
    if (t < 512) {
        const int h = t >> 8, col = t & 255;
        const int cnt = cnt_s[h];
        float s = 0.f;
        const float* base = node_f + (size_t)(b * NPB) * 256 + col;
        for (int i = 0; i < cnt; ++i) {
            int n = idx_s[h][i];
            s += w_s[h][n] * base[(size_t)n * 256];
        }
        snf_s[h][col] = s;
    } else {
        const int tt = t - 512;
        const int ha = tt >> 8, j = tt & 63, g = (tt >> 6) & 3;
        const int cnt = cnt_s[ha];
        float mu = j * MU_STEP;
        float r = 0.f;
        for (int i = g; i < cnt; i += 4) {
            int n = idx_s[ha][i];
            float uu = (d10_s[ha][n] - mu) * INV_SIG;
            r += w_s[ha][n] * __expf(-uu * uu);
        }
        red[tt] = r;
    }
    __syncthreads();
    if (t < 128) {
        int ha = t >> 6, j = t & 63;
        rj_s[ha][j] = red[ha * 256 + j] + red[ha * 256 + 64 + j]
                    + red[ha * 256 + 128 + j] + red[ha * 256 + 192 + j];
    }
    __syncthreads();

    // ---- upd wave-GEMV over raw Wkv v-rows (4 passes) ----
#pragma unroll
    for (int pass = 0; pass < 4; ++pass) {
        int m = pass * 64 + wv * 4 + sub;
        const float* wr = Wkv + (size_t)(256 + m) * 320 + kc16;
        float aAc = 0.f, aBc = 0.f;
        for (int u = 0; u < 16; u += 8) {
            float w8[8];
#pragma unroll
            for (int v = 0; v < 8; ++v) w8[v] = wr[(u + v) * 16];
#pragma unroll
            for (int v = 0; v < 8; ++v) {
                int c = kc16 + (u + v) * 16;
                aAc = fmaf(w8[v], snf_s[0][c], aAc);
                aBc = fmaf(w8[v], snf_s[1][c], aBc);
            }
        }
        {
            float w4r[4];
#pragma unroll
            for (int v = 0; v < 4; ++v) w4r[v] = wr[256 + v * 16];
#pragma unroll
            for (int v = 0; v < 4; ++v) {
                int j = kc16 + v * 16;
                aAc = fmaf(w4r[v], rj_s[0][j], aAc);
                aBc = fmaf(w4r[v], rj_s[1][j], aBc);
            }
        }
#pragma unroll
        for (int o = 8; o >= 1; o >>= 1) {
            aAc += __shfl_xor(aAc, o, 64);
            aBc += __shfl_xor(aBc, o, 64);
        }
        if (kc16 == 0) { red[m] = aAc; red[256 + m] = aBc; }
    }
    __syncthreads();

    // ---- residual + LN1 (t<512: h = t>>8, th = t&255) ----
    const int h = (t >> 8) & 1, th = t & 255;
    float x = 0.f;
    if (t < 512)
        x = af_s[h][th] + red[h * 256 + th] * (h ? invB : invA) + bkv[256 + th];
    {
        float s1 = wave_sum(x);
        if (l == 0) red16[wv] = s1;
    }
    __syncthreads();
    float meanA = (red16[0] + red16[1] + red16[2] + red16[3]) * (1.0f / 256.0f);
    float meanB = (red16[4] + red16[5] + red16[6] + red16[7]) * (1.0f / 256.0f);
    __syncthreads();
    float xc = (t < 512) ? (x - (h ? meanB : meanA)) : 0.f;
    {
        float v1 = wave_sum(xc * xc);
        if (l == 0) red16[wv] = v1;
    }
    __syncthreads();
    float varA = (red16[0] + red16[1] + red16[2] + red16[3]) * (1.0f / 256.0f);
    float varB = (red16[4] + red16[5] + red16[6] + red16[7]) * (1.0f / 256.0f);
    __syncthreads();
    if (t < 512)
        af_s[h][th] = xc * rsqrtf((h ? varB : varA) + 1e-5f) * ln1_g[th] + ln1_b[th];
    __syncthreads();

    // ---- MLP L1 (8 passes): m1 = relu(W1.af1 + b1) ----
#pragma unroll
    for (int pass = 0; pass < 8; ++pass) {
        int m = pass * 64 + wv * 4 + sub;
        const float* wr = W1 + (size_t)m * 256 + kc16;
        float aAc = 0.f, aBc = 0.f;
        for (int u = 0; u < 16; u += 8) {
            float w8[8];
#pragma unroll
            for (int v = 0; v < 8; ++v) w8[v] = wr[(u + v) * 16];
#pragma unroll
            for (int v = 0; v < 8; ++v) {
                int c = kc16 + (u + v) * 16;
                aAc = fmaf(w8[v], af_s[0][c], aAc);
                aBc = fmaf(w8[v], af_s[1][c], aBc);
            }
        }
#pragma unroll
        for (int o = 8; o >= 1; o >>= 1) {
            aAc += __shfl_xor(aAc, o, 64);
            aBc += __shfl_xor(aBc, o, 64);
        }
        if (kc16 == 0) {
            float bv = b1[m];
            m1_s[0][m] = fmaxf(aAc + bv, 0.f);
            m1_s[1][m] = fmaxf(aBc + bv, 0.f);
        }
    }
    __syncthreads();

    // ---- MLP L2 (8 passes): m2 = relu(W2.m1 + b2) ----
#pragma unroll
    for (int pass = 0; pass < 8; ++pass) {
        int m = pass * 64 + wv * 4 + sub;
        const float* wr = W2 + (size_t)m * 512 + kc16;
        float aAc = 0.f, aBc = 0.f;
        for (int u = 0; u < 32; u += 8) {
            float w8[8];
#pragma unroll
            for (int v = 0; v < 8; ++v) w8[v] = wr[(u + v) * 16];
#pragma unroll
            for (int v = 0; v < 8; ++v) {
                int c = kc16 + (u + v) * 16;
                aAc = fmaf(w8[v], m1_s[0][c], aAc);
                aBc = fmaf(w8[v], m1_s[1][c], aBc);
            }
        }
#pragma unroll
        for (int o = 8; o >= 1; o >>= 1) {
            aAc += __shfl_xor(aAc, o, 64);
            aBc += __shfl_xor(aBc, o, 64);
        }
        if (kc16 == 0) {
            float bv = b2[m];
            m2_s[0][m] = fmaxf(aAc + bv, 0.f);
            m2_s[1][m] = fmaxf(aBc + bv, 0.f);
        }
    }
    __syncthreads();

    // ---- MLP L3 (4 passes): y = W3.m2 + b3 -> red[] ----
#pragma unroll
    for (int pass = 0; pass < 4; ++pass) {
        int m = pass * 64 + wv * 4 + sub;
        const float* wr = W3 + (size_t)m * 512 + kc16;
        float aAc = 0.f, aBc = 0.f;
        for (int u = 0; u < 32; u += 8) {
            float w8[8];
#pragma unroll
            for (int v = 0; v < 8; ++v) w8[v] = wr[(u + v) * 16];
#pragma unroll
            for (int v = 0; v < 8; ++v) {
                int c = kc16 + (u + v) * 16;
                aAc = fmaf(w8[v], m2_s[0][c], aAc);
                aBc = fmaf(w8[v], m2_s[1][c], aBc);
            }
        }
#pragma unroll
        for (int o = 8; o >= 1; o >>= 1) {
            aAc += __shfl_xor(aAc, o, 64);
            aBc += __shfl_xor(aBc, o, 64);
        }
        if (kc16 == 0) {
            float bv = b3[m];
            red[m]       = aAc + bv;
            red[256 + m] = aBc + bv;
        }
    }
    __syncthreads();

    // ---- residual + LN2 -> out (t<512: h, th) ----
    float y = 0.f;
    if (t < 512) y = red[h * 256 + th] + af_s[h][th];
    {
        float s1 = wave_sum(y);
        if (l == 0) red16[wv] = s1;
    }
    __syncthreads();
    float mnA = (red16[0] + red16[1] + red16[2] + red16[3]) * (1.0f / 256.0f);
    float mnB = (red16[4] + red16[5] + red16[6] + red16[7]) * (1.0f / 256.0f);
    __syncthreads();
    float yc = (t < 512) ? (y - (h ? mnB : mnA)) : 0.f;
    {
        float v1 = wave_sum(yc * yc);
        if (l == 0) red16[wv] = v1;
    }
    __syncthreads();
    float vrA = (red16[0] + red16[1] + red16[2] + red16[3]) * (1.0f / 256.0f);
    float vrB = (red16[4] + red16[5] + red16[6] + red16[7]) * (1.0f / 256.0f);
    if (t < 512) {
        int aOut = h ? aB : aA;
        out[(size_t)aOut * 256 + th] =
            yc * rsqrtf((h ? vrB : vrA) + 1e-5f) * g2[th] + bb2[th];
    }
}

// ---------------------------------------------------------------------------
extern "C" void kernel_launch(void* const* d_in, const int* in_sizes, int n_in,
                              void* d_out, int out_size, void* d_ws, size_t ws_size,
                              hipStream_t stream)
{
    const float* anchor_x  = (const float*)d_in[0];
    const float* node_x    = (const float*)d_in[1];
    const float* anchor_f  = (const float*)d_in[2];
    const float* node_f    = (const float*)d_in[3];
    const float* node_mask = (const float*)d_in[6];
    const float* Wq        = (const float*)d_in[7];
    const float* bq        = (const float*)d_in[8];
    const float* Wkv       = (const float*)d_in[9];
    const float* bkv       = (const float*)d_in[10];
    const float* ln1_g     = (const float*)d_in[11];
    const float* ln1_b     = (const float*)d_in[12];
    const float* W1        = (const float*)d_in[13];
    const float* b1        = (const float*)d_in[14];
    const float* W2        = (const float*)d_in[15];
    const float* b2        = (const float*)d_in[16];
    const float* W3        = (const float*)d_in[17];
    const float* b3        = (const float*)d_in[18];
    const float* ln2_g     = (const float*)d_in[19];
    const float* ln2_b     = (const float*)d_in[20];

    fused_all<<<256, 1024, 0, stream>>>(anchor_x, node_x, anchor_f, node_f,
                                        node_mask, Wq, bq, Wkv, bkv,
                                        ln1_g, ln1_b, W1, b1, W2, b2, W3, b3,
                                        ln2_g, ln2_b, (float*)d_out);
}

// Round 16
// 164.565 us; speedup vs baseline: 1.4107x; 1.0100x over previous
//
#include <hip/hip_runtime.h>

// Problem constants (fixed by reference)
#define H    256
#define HE   64
#define NPB  512         // nodes per batch
#define NA   512         // total anchors (8 batches * 64)
#define MU_STEP (20.0f / 63.0f)
#define INV_SIG 3.2f     // 1/0.3125

// ---------------------------------------------------------------------------
__device__ __forceinline__ float wave_sum(float v) {
#pragma unroll
    for (int o = 32; o; o >>= 1) v += __shfl_xor(v, o, 64);
    return v;
}
__device__ __forceinline__ float wave_max(float v) {
#pragma unroll
    for (int o = 32; o; o >>= 1) v = fmaxf(v, __shfl_xor(v, o, 64));
    return v;
}
__device__ __forceinline__ float block_sum1024(float v, float* red16, int t) {
    v = wave_sum(v);
    if ((t & 63) == 0) red16[t >> 6] = v;
    __syncthreads();
    v = 0.f;
#pragma unroll
    for (int i = 0; i < 16; ++i) v += red16[i];
    __syncthreads();
    return v;
}

// ---------------------------------------------------------------------------
// Single kernel: everything, 2 anchors per block, raw weights.
// 256 blocks x 1024 threads (16 waves/CU). aA=(bid&7)*64+2*(bid>>3), aB=aA+1.
// Phase C barrier-free with depth-2 global prefetch; wave-GEMVs use 16-load
// flights (whole K=256 pass outstanding at once) for 2x memory-level par.
// ---------------------------------------------------------------------------
__global__ void __launch_bounds__(1024) fused_all(
    const float* __restrict__ anchor_x, const float* __restrict__ node_x,
    const float* __restrict__ anchor_f, const float* __restrict__ node_f,
    const float* __restrict__ node_mask,
    const float* __restrict__ Wq,  const float* __restrict__ bq,
    const float* __restrict__ Wkv, const float* __restrict__ bkv,
    const float* __restrict__ ln1_g, const float* __restrict__ ln1_b,
    const float* __restrict__ W1, const float* __restrict__ b1,
    const float* __restrict__ W2, const float* __restrict__ b2,
    const float* __restrict__ W3, const float* __restrict__ b3,
    const float* __restrict__ g2,  const float* __restrict__ bb2,
    float* __restrict__ out)
{
    const int bid = blockIdx.x;
    const int b  = bid & 7;                  // batch -> XCD
    const int pr = bid >> 3;                 // anchor pair 0..31
    const int aA = b * 64 + 2 * pr;
    const int aB = aA + 1;
    const int t  = threadIdx.x;              // 0..1023
    const int wv = t >> 6, l = t & 63;       // wave id (0..15), lane
    const int sub = l >> 4, kc16 = l & 15;   // wave-GEMV: output-sub, k-chunk

    __shared__ __align__(16) float qWe_s[2][324];  // qW 0-255, qe 256-319
    __shared__ float q_s[2][256];
    __shared__ float af_s[2][256];           // anchor_f, later af1
    __shared__ float d10_s[2][NPB];
    __shared__ float mf_s[NPB];
    __shared__ float lg_s[2][NPB];
    __shared__ float w_s[2][NPB];
    __shared__ float snf_s[2][256], rj_s[2][64];
    __shared__ float m1_s[2][512], m2_s[2][512];
    __shared__ float red[512], red16[16];
    __shared__ int   idx_s[2][NPB];
    __shared__ int   cnt_s[2];

    if (t < 256)       af_s[0][t]        = anchor_f[(size_t)aA * 256 + t];
    else if (t < 512)  af_s[1][t - 256]  = anchor_f[(size_t)aB * 256 + (t - 256)];
    if (t < 2) cnt_s[t] = 0;

    // Phase A: d10 for both anchors + mask factor, one node per thread (t<512)
    if (t < 512) {
        float axA0 = anchor_x[3 * aA], axA1 = anchor_x[3 * aA + 1], axA2 = anchor_x[3 * aA + 2];
        float axB0 = anchor_x[3 * aB], axB1 = anchor_x[3 * aB + 1], axB2 = anchor_x[3 * aB + 2];
        int ng = b * NPB + t;
        float nx0 = node_x[3 * ng], nx1 = node_x[3 * ng + 1], nx2 = node_x[3 * ng + 2];
        float dx = axA0 - nx0 + 1e-8f, dy = axA1 - nx1 + 1e-8f, dz = axA2 - nx2 + 1e-8f;
        d10_s[0][t] = sqrtf(dx * dx + dy * dy + dz * dz) * 0.1f;
        dx = axB0 - nx0 + 1e-8f; dy = axB1 - nx1 + 1e-8f; dz = axB2 - nx2 + 1e-8f;
        d10_s[1][t] = sqrtf(dx * dx + dy * dy + dz * dz) * 0.1f;
        mf_s[t] = (node_mask[ng] - 1.0f) * 1000000.0f;
    }
    __syncthreads();   // af_s, cnt_s, d10_s, mf_s ready

    // ---- Phase B1: q[m] = bq[m] + Wq[m,:].af  (wave-GEMV, 16-load flight) ----
#pragma unroll
    for (int pass = 0; pass < 4; ++pass) {
        int m = pass * 64 + wv * 4 + sub;
        const float* wr = Wq + (size_t)m * 256 + kc16;
        float w16[16];
#pragma unroll
        for (int v = 0; v < 16; ++v) w16[v] = wr[v * 16];
        float aAc = 0.f, aBc = 0.f;
#pragma unroll
        for (int v = 0; v < 16; ++v) {
            int c = kc16 + v * 16;
            aAc = fmaf(w16[v], af_s[0][c], aAc);
            aBc = fmaf(w16[v], af_s[1][c], aBc);
        }
#pragma unroll
        for (int o = 8; o >= 1; o >>= 1) {
            aAc += __shfl_xor(aAc, o, 64);
            aBc += __shfl_xor(aBc, o, 64);
        }
        if (kc16 == 0) {
            float bv = bq[m];
            q_s[0][m] = aAc + bv;
            q_s[1][m] = aBc + bv;
        }
    }
    __syncthreads();   // q_s ready

    // ---- Phase B2: qW/qe column walk over raw Wkv rows 0..255 (16-batch) ----
    {
        int ha = -1, col = 0;
        if (t < 320)                   { ha = 0; col = t; }
        else if (t >= 512 && t < 832)  { ha = 1; col = t - 512; }
        if (ha >= 0) {
            const float* qs = q_s[ha];
            float acc = 0.f;
            for (int o = 0; o < 256; o += 16) {
                float w16[16];
#pragma unroll
                for (int u = 0; u < 16; ++u) w16[u] = Wkv[(size_t)(o + u) * 320 + col];
#pragma unroll
                for (int u = 0; u < 16; ++u) acc = fmaf(w16[u], qs[o + u], acc);
            }
            qWe_s[ha][col] = acc;
        }
    }
    // qbk via block reductions (their syncs publish qWe_s)
    float qbkA = block_sum1024((t < 256) ? q_s[0][t] * bkv[t] : 0.f, red16, t);
    float qbkB = block_sum1024((t < 256) ? q_s[1][t] * bkv[t] : 0.f, red16, t);

    // ---- Phase C: logits, barrier-free, depth-2 prefetch ----
    {
        const float4 qA = ((const float4*)qWe_s[0])[l];
        const float4 qB = ((const float4*)qWe_s[1])[l];
        const float qeA = qWe_s[0][256 + l], qeB = qWe_s[1][256 + l];
        const float muL = l * MU_STEP;
        const float4* nfb = (const float4*)(node_f + (size_t)(b * NPB) * 256);

        float4 f0 = nfb[(size_t)wv * 64 + l];
        float4 f1 = nfb[(size_t)(wv + 16) * 64 + l];
        for (int it = 0; it < 32; ++it) {
            const int n = wv + it * 16;
            float4 fn;
            if (it < 30) fn = nfb[(size_t)(n + 32) * 64 + l];

            float sA = qA.x * f0.x + qA.y * f0.y + qA.z * f0.z + qA.w * f0.w;
            float sB = qB.x * f0.x + qB.y * f0.y + qB.z * f0.z + qB.w * f0.w;
            float dA10 = d10_s[0][n], dB10 = d10_s[1][n];   // wave-uniform
            float u = (dA10 - muL) * INV_SIG; sA = fmaf(qeA, __expf(-u * u), sA);
            u = (dB10 - muL) * INV_SIG;       sB = fmaf(qeB, __expf(-u * u), sB);
#pragma unroll
            for (int o = 1; o < 64; o <<= 1) {
                sA += __shfl_xor(sA, o, 64);
                sB += __shfl_xor(sB, o, 64);
            }
            if (l == 0) {
                lg_s[0][n] = (sA + qbkA) * mf_s[n];
                lg_s[1][n] = (sB + qbkB) * mf_s[n];
            }
            f0 = f1; f1 = fn;
        }
    }
    __syncthreads();

    // ---- Phase D: softmax (anchor h8 = t>>9, node n9 = t&511) ----
    const int h8 = t >> 9, n9 = t & 511;
    float lg = lg_s[h8][n9];
    {
        float m = wave_max(lg);
        if (l == 0) red16[wv] = m;
    }
    __syncthreads();
    float gmA = red16[0], gmB = red16[8];
#pragma unroll
    for (int i = 1; i < 8; ++i) { gmA = fmaxf(gmA, red16[i]); gmB = fmaxf(gmB, red16[8 + i]); }
    __syncthreads();
    float e = __expf(lg - (h8 ? gmB : gmA));
    w_s[h8][n9] = e;
    {
        float sm = wave_sum(e);
        if (l == 0) red16[wv] = sm;
    }
    __syncthreads();
    float smA = 0.f, smB = 0.f;
#pragma unroll
    for (int i = 0; i < 8; ++i) { smA += red16[i]; smB += red16[8 + i]; }
    const float invA = 1.0f / smA, invB = 1.0f / smB;
    if (e > 0.f) { int p = atomicAdd(&cnt_s[h8], 1); idx_s[h8][p] = n9; }
    __syncthreads();

    // ---- snf (t<512) || rj partials (t>=512), fully parallel ----
    if (t < 512) {
        const int hh = t >> 8, col = t & 255;
        const int cnt = cnt_s[hh];
        float s = 0.f;
        const float* base = node_f + (size_t)(b * NPB) * 256 + col;
        for (int i = 0; i < cnt; ++i) {
            int n = idx_s[hh][i];
            s += w_s[hh][n] * base[(size_t)n * 256];
        }
        snf_s[hh][col] = s;
    } else {
        const int tt = t - 512;
        const int ha = tt >> 8, j = tt & 63, g = (tt >> 6) & 3;
        const int cnt = cnt_s[ha];
        float mu = j * MU_STEP;
        float r = 0.f;
        for (int i = g; i < cnt; i += 4) {
            int n = idx_s[ha][i];
            float uu = (d10_s[ha][n] - mu) * INV_SIG;
            r += w_s[ha][n] * __expf(-uu * uu);
        }
        red[tt] = r;
    }
    __syncthreads();
    if (t < 128) {
        int ha = t >> 6, j = t & 63;
        rj_s[ha][j] = red[ha * 256 + j] + red[ha * 256 + 64 + j]
                    + red[ha * 256 + 128 + j] + red[ha * 256 + 192 + j];
    }
    __syncthreads();

    // ---- upd wave-GEMV over raw Wkv v-rows (16+4 load flight) ----
#pragma unroll
    for (int pass = 0; pass < 4; ++pass) {
        int m = pass * 64 + wv * 4 + sub;
        const float* wr = Wkv + (size_t)(256 + m) * 320 + kc16;
        float w16[16], w4r[4];
#pragma unroll
        for (int v = 0; v < 16; ++v) w16[v] = wr[v * 16];
#pragma unroll
        for (int v = 0; v < 4; ++v) w4r[v] = wr[256 + v * 16];
        float aAc = 0.f, aBc = 0.f;
#pragma unroll
        for (int v = 0; v < 16; ++v) {
            int c = kc16 + v * 16;
            aAc = fmaf(w16[v], snf_s[0][c], aAc);
            aBc = fmaf(w16[v], snf_s[1][c], aBc);
        }
#pragma unroll
        for (int v = 0; v < 4; ++v) {
            int j = kc16 + v * 16;
            aAc = fmaf(w4r[v], rj_s[0][j], aAc);
            aBc = fmaf(w4r[v], rj_s[1][j], aBc);
        }
#pragma unroll
        for (int o = 8; o >= 1; o >>= 1) {
            aAc += __shfl_xor(aAc, o, 64);
            aBc += __shfl_xor(aBc, o, 64);
        }
        if (kc16 == 0) { red[m] = aAc; red[256 + m] = aBc; }
    }
    __syncthreads();

    // ---- residual + LN1 (t<512: h = t>>8, th = t&255) ----
    const int h = (t >> 8) & 1, th = t & 255;
    float x = 0.f;
    if (t < 512)
        x = af_s[h][th] + red[h * 256 + th] * (h ? invB : invA) + bkv[256 + th];
    {
        float s1 = wave_sum(x);
        if (l == 0) red16[wv] = s1;
    }
    __syncthreads();
    float meanA = (red16[0] + red16[1] + red16[2] + red16[3]) * (1.0f / 256.0f);
    float meanB = (red16[4] + red16[5] + red16[6] + red16[7]) * (1.0f / 256.0f);
    __syncthreads();
    float xc = (t < 512) ? (x - (h ? meanB : meanA)) : 0.f;
    {
        float v1 = wave_sum(xc * xc);
        if (l == 0) red16[wv] = v1;
    }
    __syncthreads();
    float varA = (red16[0] + red16[1] + red16[2] + red16[3]) * (1.0f / 256.0f);
    float varB = (red16[4] + red16[5] + red16[6] + red16[7]) * (1.0f / 256.0f);
    __syncthreads();
    if (t < 512)
        af_s[h][th] = xc * rsqrtf((h ? varB : varA) + 1e-5f) * ln1_g[th] + ln1_b[th];
    __syncthreads();

    // ---- MLP L1 (8 passes, 16-load flight): m1 = relu(W1.af1 + b1) ----
#pragma unroll
    for (int pass = 0; pass < 8; ++pass) {
        int m = pass * 64 + wv * 4 + sub;
        const float* wr = W1 + (size_t)m * 256 + kc16;
        float w16[16];
#pragma unroll
        for (int v = 0; v < 16; ++v) w16[v] = wr[v * 16];
        float aAc = 0.f, aBc = 0.f;
#pragma unroll
        for (int v = 0; v < 16; ++v) {
            int c = kc16 + v * 16;
            aAc = fmaf(w16[v], af_s[0][c], aAc);
            aBc = fmaf(w16[v], af_s[1][c], aBc);
        }
#pragma unroll
        for (int o = 8; o >= 1; o >>= 1) {
            aAc += __shfl_xor(aAc, o, 64);
            aBc += __shfl_xor(aBc, o, 64);
        }
        if (kc16 == 0) {
            float bv = b1[m];
            m1_s[0][m] = fmaxf(aAc + bv, 0.f);
            m1_s[1][m] = fmaxf(aBc + bv, 0.f);
        }
    }
    __syncthreads();

    // ---- MLP L2 (8 passes, 2x16-load flights): m2 = relu(W2.m1 + b2) ----
#pragma unroll
    for (int pass = 0; pass < 8; ++pass) {
        int m = pass * 64 + wv * 4 + sub;
        const float* wr = W2 + (size_t)m * 512 + kc16;
        float aAc = 0.f, aBc = 0.f;
#pragma unroll
        for (int u = 0; u < 32; u += 16) {
            float w16[16];
#pragma unroll
            for (int v = 0; v < 16; ++v) w16[v] = wr[(u + v) * 16];
#pragma unroll
            for (int v = 0; v < 16; ++v) {
                int c = kc16 + (u + v) * 16;
                aAc = fmaf(w16[v], m1_s[0][c], aAc);
                aBc = fmaf(w16[v], m1_s[1][c], aBc);
            }
        }
#pragma unroll
        for (int o = 8; o >= 1; o >>= 1) {
            aAc += __shfl_xor(aAc, o, 64);
            aBc += __shfl_xor(aBc, o, 64);
        }
        if (kc16 == 0) {
            float bv = b2[m];
            m2_s[0][m] = fmaxf(aAc + bv, 0.f);
            m2_s[1][m] = fmaxf(aBc + bv, 0.f);
        }
    }
    __syncthreads();

    // ---- MLP L3 (4 passes, 2x16-load flights): y = W3.m2 + b3 -> red[] ----
#pragma unroll
    for (int pass = 0; pass < 4; ++pass) {
        int m = pass * 64 + wv * 4 + sub;
        const float* wr = W3 + (size_t)m * 512 + kc16;
        float aAc = 0.f, aBc = 0.f;
#pragma unroll
        for (int u = 0; u < 32; u += 16) {
            float w16[16];
#pragma unroll
            for (int v = 0; v < 16; ++v) w16[v] = wr[(u + v) * 16];
#pragma unroll
            for (int v = 0; v < 16; ++v) {
                int c = kc16 + (u + v) * 16;
                aAc = fmaf(w16[v], m2_s[0][c], aAc);
                aBc = fmaf(w16[v], m2_s[1][c], aBc);
            }
        }
#pragma unroll
        for (int o = 8; o >= 1; o >>= 1) {
            aAc += __shfl_xor(aAc, o, 64);
            aBc += __shfl_xor(aBc, o, 64);
        }
        if (kc16 == 0) {
            float bv = b3[m];
            red[m]       = aAc + bv;
            red[256 + m] = aBc + bv;
        }
    }
    __syncthreads();

    // ---- residual + LN2 -> out (t<512: h, th) ----
    float y = 0.f;
    if (t < 512) y = red[h * 256 + th] + af_s[h][th];
    {
        float s1 = wave_sum(y);
        if (l == 0) red16[wv] = s1;
    }
    __syncthreads();
    float mnA = (red16[0] + red16[1] + red16[2] + red16[3]) * (1.0f / 256.0f);
    float mnB = (red16[4] + red16[5] + red16[6] + red16[7]) * (1.0f / 256.0f);
    __syncthreads();
    float yc = (t < 512) ? (y - (h ? mnB : mnA)) : 0.f;
    {
        float v1 = wave_sum(yc * yc);
        if (l == 0) red16[wv] = v1;
    }
    __syncthreads();
    float vrA = (red16[0] + red16[1] + red16[2] + red16[3]) * (1.0f / 256.0f);
    float vrB = (red16[4] + red16[5] + red16[6] + red16[7]) * (1.0f / 256.0f);
    if (t < 512) {
        int aOut = h ? aB : aA;
        out[(size_t)aOut * 256 + th] =
            yc * rsqrtf((h ? vrB : vrA) + 1e-5f) * g2[th] + bb2[th];
    }
}

// ---------------------------------------------------------------------------
extern "C" void kernel_launch(void* const* d_in, const int* in_sizes, int n_in,
                              void* d_out, int out_size, void* d_ws, size_t ws_size,
                              hipStream_t stream)
{
    const float* anchor_x  = (const float*)d_in[0];
    const float* node_x    = (const float*)d_in[1];
    const float* anchor_f  = (const float*)d_in[2];
    const float* node_f    = (const float*)d_in[3];
    const float* node_mask = (const float*)d_in[6];
    const float* Wq        = (const float*)d_in[7];
    const float* bq        = (const float*)d_in[8];
    const float* Wkv       = (const float*)d_in[9];
    const float* bkv       = (const float*)d_in[10];
    const float* ln1_g     = (const float*)d_in[11];
    const float* ln1_b     = (const float*)d_in[12];
    const float* W1        = (const float*)d_in[13];
    const float* b1        = (const float*)d_in[14];
    const float* W2        = (const float*)d_in[15];
    const float* b2        = (const float*)d_in[16];
    const float* W3        = (const float*)d_in[17];
    const float* b3        = (const float*)d_in[18];
    const float* ln2_g     = (const float*)d_in[19];
    const float* ln2_b     = (const float*)d_in[20];

    fused_all<<<256, 1024, 0, stream>>>(anchor_x, node_x, anchor_f, node_f,
                                        node_mask, Wq, bq, Wkv, bkv,
                                        ln1_g, ln1_b, W1, b1, W2, b2, W3, b3,
                                        ln2_g, ln2_b, (float*)d_out);
}